// Round 8
// baseline (2408.725 us; speedup 1.0000x reference)
//
#include <hip/hip_runtime.h>
#include <hip/hip_bf16.h>
#include <math.h>

namespace {

constexpr int BB = 8;
constexpr int LL = 768;
constexpr int DD = 512;
constexpr int L2E = LL * LL;
constexpr float NEGF = -1e9f;

__device__ __forceinline__ float softplus_f(float x) {
  return x > 0.f ? x + log1pf(expf(-x)) : log1pf(expf(x));
}
__device__ __forceinline__ float logsigmoid_f(float x) {
  return x > 0.f ? -log1pf(expf(-x)) : x - log1pf(expf(x));
}

// diag-compact: diag s = r + c (0-based), element index Jext(s, r)
__device__ __forceinline__ int doffc(int s) {
  return (s <= LL - 1) ? ((s * (s + 1)) >> 1)
                       : (L2E - (((2 * LL - 1 - s) * (2 * LL - s)) >> 1));
}
__device__ __forceinline__ int Jext(int s, int r) {
  return doffc(s) + r - ((s > LL - 1) ? (s - (LL - 1)) : 0);
}
__device__ __forceinline__ int dJa(int s) { return (s <= LL - 2) ? s + 1 : 2 * LL - 2 - s; }
__device__ __forceinline__ int dJd(int s) { return (s <= LL - 1) ? -s : s - (2 * LL - 1); }

// -------- Kernel A: out[r][c] = sum_d X[r][d] * W[c][d] + bias[c] --------
__global__ __launch_bounds__(256) void linear_kernel(
    const float* __restrict__ hx, const float* __restrict__ hy,
    const float* __restrict__ Wm, const float* __restrict__ bm,
    const float* __restrict__ Wg, const float* __restrict__ bg,
    float* __restrict__ zx, float* __restrict__ zy,
    float* __restrict__ gx, float* __restrict__ gy) {
  constexpr int BK = 16;
  __shared__ float Xs[BK][64 + 1];
  __shared__ float Ws[BK][64 + 1];

  const int which = blockIdx.z;
  const float* Xin  = (which & 1) ? hy : hx;
  const float* W    = (which >= 2) ? Wg : Wm;
  const float* bias = (which >= 2) ? bg : bm;
  float* out = (which == 0) ? zx : (which == 1) ? zy : (which == 2) ? gx : gy;

  const int row0 = blockIdx.y * 64;
  const int col0 = blockIdx.x * 64;
  const int t  = threadIdx.x;
  const int tx = t & 15;
  const int ty = t >> 4;
  const int lrow = t >> 2;
  const int lseg = (t & 3) * 4;

  float acc[4][4] = {};
  for (int k0 = 0; k0 < DD; k0 += BK) {
    const float4 xv = *(const float4*)(Xin + (size_t)(row0 + lrow) * DD + k0 + lseg);
    const float4 wv = *(const float4*)(W   + (size_t)(col0 + lrow) * DD + k0 + lseg);
    Xs[lseg + 0][lrow] = xv.x; Xs[lseg + 1][lrow] = xv.y;
    Xs[lseg + 2][lrow] = xv.z; Xs[lseg + 3][lrow] = xv.w;
    Ws[lseg + 0][lrow] = wv.x; Ws[lseg + 1][lrow] = wv.y;
    Ws[lseg + 2][lrow] = wv.z; Ws[lseg + 3][lrow] = wv.w;
    __syncthreads();
#pragma unroll
    for (int kk = 0; kk < BK; ++kk) {
      float xr[4], wr[4];
#pragma unroll
      for (int a = 0; a < 4; ++a) xr[a] = Xs[kk][ty * 4 + a];
#pragma unroll
      for (int b = 0; b < 4; ++b) wr[b] = Ws[kk][tx * 4 + b];
#pragma unroll
      for (int a = 0; a < 4; ++a)
#pragma unroll
        for (int b = 0; b < 4; ++b) acc[a][b] += xr[a] * wr[b];
    }
    __syncthreads();
  }
#pragma unroll
  for (int a = 0; a < 4; ++a) {
    const int r = row0 + ty * 4 + a;
#pragma unroll
    for (int b2 = 0; b2 < 4; ++b2) {
      const int c = col0 + tx * 4 + b2;
      out[(size_t)r * DD + c] = acc[a][b2] + bias[c];
    }
  }
}

// -------- Kernel B: theta/A batched logits --------
__global__ __launch_bounds__(256) void logits_kernel(
    const float* __restrict__ zx, const float* __restrict__ zy,
    const float* __restrict__ gx, const float* __restrict__ gy,
    float* __restrict__ theta, float* __restrict__ Aout) {
  constexpr int BK = 16;
  __shared__ float Xs[BK][64 + 1];
  __shared__ float Ys[BK][64 + 1];

  const int bz = blockIdx.z;
  const int b = bz >> 1, w = bz & 1;
  const float* X = (w ? gx : zx) + (size_t)b * LL * DD;
  const float* Y = (w ? gy : zy) + (size_t)b * LL * DD;
  float* out = (w ? Aout : theta) + (size_t)b * L2E;

  const int row0 = blockIdx.y * 64;
  const int col0 = blockIdx.x * 64;
  const int t  = threadIdx.x;
  const int tx = t & 15;
  const int ty = t >> 4;
  const int lrow = t >> 2;
  const int lseg = (t & 3) * 4;

  float acc[4][4] = {};
  for (int k0 = 0; k0 < DD; k0 += BK) {
    const float4 xv = *(const float4*)(X + (size_t)(row0 + lrow) * DD + k0 + lseg);
    const float4 yv = *(const float4*)(Y + (size_t)(col0 + lrow) * DD + k0 + lseg);
    Xs[lseg + 0][lrow] = xv.x; Xs[lseg + 1][lrow] = xv.y;
    Xs[lseg + 2][lrow] = xv.z; Xs[lseg + 3][lrow] = xv.w;
    Ys[lseg + 0][lrow] = yv.x; Ys[lseg + 1][lrow] = yv.y;
    Ys[lseg + 2][lrow] = yv.z; Ys[lseg + 3][lrow] = yv.w;
    __syncthreads();
#pragma unroll
    for (int kk = 0; kk < BK; ++kk) {
      float xr[4], yr[4];
#pragma unroll
      for (int a = 0; a < 4; ++a) xr[a] = Xs[kk][ty * 4 + a];
#pragma unroll
      for (int b2 = 0; b2 < 4; ++b2) yr[b2] = Ys[kk][tx * 4 + b2];
#pragma unroll
      for (int a = 0; a < 4; ++a)
#pragma unroll
        for (int b2 = 0; b2 < 4; ++b2) acc[a][b2] += xr[a] * yr[b2];
    }
    __syncthreads();
  }
#pragma unroll
  for (int a = 0; a < 4; ++a) {
    const int r = row0 + ty * 4 + a;
#pragma unroll
    for (int b2 = 0; b2 < 4; ++b2) {
      const int c = col0 + tx * 4 + b2;
      const float v = acc[a][b2];
      out[(size_t)r * LL + c] = w ? logsigmoid_f(v) : softplus_f(v);
    }
  }
}

// -------- row-major theta,A -> packed diag-compact float2 (th, a) --------
__global__ __launch_bounds__(256) void row2diag(
    const float* __restrict__ theta, const float* __restrict__ A,
    float2* __restrict__ thaa) {
  __shared__ float tT[64 * 66];
  __shared__ float tA[64 * 66];
  const int b = blockIdx.z;
  const float* inT = theta + (size_t)b * L2E;
  const float* inA = A + (size_t)b * L2E;
  float2* out = thaa + (size_t)b * L2E;
  const int r0 = blockIdx.y * 64, c0 = blockIdx.x * 64;
  const int t = threadIdx.x, lane = t & 63, grp = t >> 6;
  for (int it = 0; it < 16; ++it) {
    const int rr = it * 4 + grp;
    tT[rr * 66 + lane] = inT[(size_t)(r0 + rr) * LL + c0 + lane];
    tA[rr * 66 + lane] = inA[(size_t)(r0 + rr) * LL + c0 + lane];
  }
  __syncthreads();
  for (int si = grp; si < 127; si += 4) {
    const int s = r0 + c0 + si;
    const int rlo = max(r0, s - c0 - 63);
    const int rhi = min(r0 + 63, s - c0);
    const int r = rlo + lane;
    if (r <= rhi) {
      const int ii = (r - r0) * 66 + (s - r - c0);
      out[doffc(s) + r - max(0, s - (LL - 1))] = make_float2(tT[ii], tA[ii]);
    }
  }
}

// -------- diag-compact bf16 E -> row-major fp32 (aln) --------
__global__ __launch_bounds__(256) void diag2row(
    const __hip_bfloat16* __restrict__ Ed, float* __restrict__ aln) {
  __shared__ float tile[64 * 66];
  const int b = blockIdx.z;
  const int r0 = blockIdx.y * 64;
  const int c0 = blockIdx.x * 64;
  const __hip_bfloat16* E = Ed + (size_t)b * L2E;
  float* out = aln + (size_t)b * L2E;
  const int t = threadIdx.x;
  const int lane = t & 63;
  const int grp = t >> 6;
  for (int si = grp; si < 127; si += 4) {
    const int s = r0 + c0 + si;
    const int rlo = max(r0, s - c0 - 63);
    const int rhi = min(r0 + 63, s - c0);
    const int r = rlo + lane;
    if (r <= rhi) {
      tile[(r - r0) * 66 + (s - r - c0)] =
          __bfloat162float(E[doffc(s) + r - max(0, s - (LL - 1))]);
    }
  }
  __syncthreads();
  for (int it = 0; it < 16; ++it) {
    const int rr = it * 4 + grp;
    out[(size_t)(r0 + rr) * LL + c0 + lane] = tile[rr * 66 + lane];
  }
}

// publish flag: LDS-only release (ring data is LDS; avoid vmcnt(0) drain of
// global stores that a full RELEASE store would force)
__device__ __forceinline__ void lds_release_store(int* p, int v) {
  asm volatile("s_waitcnt lgkmcnt(0)" ::: "memory");
  __hip_atomic_store(p, v, __ATOMIC_RELAXED, __HIP_MEMORY_SCOPE_WORKGROUP);
}

// -------- Fused NW fwd+bwd: 4 rows/lane, 3 waves, 32-deep shared rings --------
// Identical sync/recurrence structure to the proven R7 engine. Changes:
// (1) E goes to its OWN bf16 buffer (no V-aliasing -> no per-step vmcnt drain)
// (2) prefetch depth 2 (slot = k&1) -> live state fits VGPRs, no spills
// (3) flag publishes use lgkmcnt-only release.
__global__ __launch_bounds__(192, 1) void nw_fused(
    const float2* __restrict__ thaa, float* __restrict__ Vd,
    __hip_bfloat16* __restrict__ Ed) {
  extern __shared__ float smf[];
  int* Pf = (int*)smf;          // [4] fwd producer progress (last k published)
  int* Cf = (int*)smf + 4;      // [4] fwd consumer progress
  int* Pb = (int*)smf + 8;      // [4] bwd producer progress (descending)
  int* Cb = (int*)smf + 12;     // [4] bwd consumer progress (descending)
  float* RVf = smf + 16;        // [32][192] fwd V ring
  float* RVb = RVf + 32 * 192;  // [32][192] bwd V ring
  float* REb = RVb + 32 * 192;  // [32][192] bwd E ring

  const int b = blockIdx.x;
  const float2* TA = thaa + (size_t)b * L2E;
  float* V = Vd + (size_t)b * L2E;
  __hip_bfloat16* Eo = Ed + (size_t)b * L2E;

  const int t = threadIdx.x;
  const int w = t >> 6, l = t & 63;
  const int rowb = 4 * t;
  const int kb = 256 * w + 2;
  const int ke = kb + 1023;

  if (t < 4) {
    Pf[t] = 0;            Cf[t] = 256 * t + 1;     // kb_t - 1
    Pb[t] = 0x7fffffff;   Cb[t] = 256 * t + 1026;  // ke_t + 1
  }
  __syncthreads();

  // ================= forward =================
  {
    float2 pq[2][4];
#pragma unroll
    for (int d0 = 0; d0 < 2; ++d0) {
      const int k0 = kb + d0, slot = k0 & 1;
      const int ii = Jext(k0 - 2, rowb);
#pragma unroll
      for (int r = 0; r < 4; ++r) pq[slot][r] = TA[ii + r];
    }
    int sL = kb, iL = Jext(kb, rowb);          // refill source s = k
    int sS = kb - 2, iS = Jext(sS, rowb);      // V store s = k-2
    float p1[4], p2[4];
#pragma unroll
    for (int r = 0; r < 4; ++r) { p1[r] = NEGF; p2[r] = NEGF; }
    float rvh = NEGF;
    const int rdT = (t == 0) ? 0 : (t - 1);

    for (int kg = kb; kg < kb + 1024; kg += 8) {
      if (l == 0 && w > 0 && kg < kb + 768) {
        const int need = min(kg + 6, kb + 766);
        while (__hip_atomic_load(&Pf[w - 1], __ATOMIC_ACQUIRE,
                                 __HIP_MEMORY_SCOPE_WORKGROUP) < need) {}
      }
      if (l == 63 && w < 2) {  // back-pressure: don't overrun consumer by >24
        while (__hip_atomic_load(&Cf[w + 1], __ATOMIC_ACQUIRE,
                                 __HIP_MEMORY_SCOPE_WORKGROUP) < kg - 24) {}
      }
#pragma unroll
      for (int u = 0; u < 8; ++u) {
        const int k = kg + u;
        const int su = (kg + u) & 1;  // static: kg even
        const int k31 = k & 31, m31 = (k - 1) & 31;
        float rv = RVf[m31 * 192 + rdT];
        if (l == 0 && w == 0) rv = NEGF;
        float rdg = rvh;
        if (l == 0 && w == 0) rdg = (k == 2) ? 0.f : NEGF;
        const int d = k - rowb - 2;
        float vv[4];
#pragma unroll
        for (int r = 0; r < 4; ++r) {
          const float Vl = p1[r];
          const float Vu = (r == 0) ? rv : p1[r - 1];
          const float Vg = (r == 0) ? rdg : p2[r - 1];
          const float av = pq[su][r].y, tv = pq[su][r].x;
          const float lft = av + Vl, up = av + Vu;
          const float mx = fmaxf(Vg, fmaxf(lft, up));
          const float val = tv + mx +
              __logf(__expf(Vg - mx) + __expf(lft - mx) + __expf(up - mx));
          vv[r] = ((unsigned)(d - r) <= 767u) ? val : NEGF;
        }
#pragma unroll
        for (int r = 0; r < 4; ++r) pq[su][r] = TA[iL + r];  // for step k+2
        iL += dJa(sL); ++sL;
#pragma unroll
        for (int r = 0; r < 4; ++r)
          if ((unsigned)(d - r) <= 767u) V[iS + r] = vv[r];
        iS += dJa(sS); ++sS;
        RVf[k31 * 192 + t] = vv[3];
        rvh = rv;
#pragma unroll
        for (int r = 0; r < 4; ++r) { p2[r] = p1[r]; p1[r] = vv[r]; }
        asm volatile("" ::: "memory");
      }
      if (l == 63 && w < 2) lds_release_store(&Pf[w], kg + 7);
      if (l == 0 && w > 0)  lds_release_store(&Cf[w], kg + 7);
    }
  }
  __syncthreads();

  // ================= backward =================
  {
    float sVv[2][4];     // V at s=k-2, rows rowb..rowb+3
    float sKt[2][4];     // th at s=k,  rows rowb+1..rowb+4
    float2 sK1[2][5];    // (th, a) at s=k-1, rows rowb..rowb+4
#pragma unroll
    for (int d0 = 0; d0 < 2; ++d0) {
      const int k0 = ke - d0, slot = k0 & 1;
      const int jV = Jext(k0 - 2, rowb);
      const int jK = Jext(k0, rowb);
      const int jK1 = Jext(k0 - 1, rowb);
#pragma unroll
      for (int r = 0; r < 4; ++r) sVv[slot][r] = V[jV + r];
#pragma unroll
      for (int r = 0; r < 4; ++r) sKt[slot][r] = TA[jK + 1 + r].x;
#pragma unroll
      for (int r = 0; r < 5; ++r) sK1[slot][r] = TA[jK1 + r];
    }
    int sV_ = ke - 4, iV = Jext(sV_, rowb);     // refill source s = k-4
    int sKc = ke - 2, iK = Jext(sKc, rowb);     // refill source s = k-2
    int sK1s = ke - 3, iK1 = Jext(sK1s, rowb);  // refill source s = k-3
    int sE = ke - 2, iE = Jext(sE, rowb);
    float N1v[4], N1e[4], N2v[4], N2e[4], hV[4], hE[4];
#pragma unroll
    for (int r = 0; r < 4; ++r) {
      N1v[r] = 0.f; N1e[r] = 0.f; N2v[r] = 0.f; N2e[r] = 0.f; hV[r] = 0.f; hE[r] = 0.f;
    }
    const int rdU = (t == 191) ? 191 : (t + 1);

    for (int kg = ke; kg > ke - 1024; kg -= 8) {
      if (l == 63 && w < 2 && kg >= kb + 255) {
        const int need = max(kg - 6, kb + 256);
        while (__hip_atomic_load(&Pb[w + 1], __ATOMIC_ACQUIRE,
                                 __HIP_MEMORY_SCOPE_WORKGROUP) > need) {}
      }
      if (l == 0 && w > 0) {  // back-pressure vs consumer below
        while (__hip_atomic_load(&Cb[w - 1], __ATOMIC_ACQUIRE,
                                 __HIP_MEMORY_SCOPE_WORKGROUP) > kg + 23) {}
      }
#pragma unroll
      for (int u = 0; u < 8; ++u) {
        const int k = kg - u;
        const int su = (kg - u) & 1;  // static: kg odd (ke odd)
        const int k31 = k & 31, p31 = (k + 1) & 31;
        N1v[3] = RVb[p31 * 192 + rdU];
        N1e[3] = REb[p31 * 192 + rdU];
        const int d = k - rowb - 2;
        float e[4], vc[4];
#pragma unroll
        for (int r = 0; r < 4; ++r) {
          vc[r] = sVv[su][r];
          const bool ok  = (unsigned)(d - r) <= 767u;
          const bool jlt = (d - r) < 767;
          const bool ilt = (rowb + r) < 767;
          float acc = 0.f;
          if (ilt && jlt) acc += N2e[r] * __expf(vc[r] - N2v[r] + sKt[su][r]);
          if (jlt) acc += hE[r] * __expf(sK1[su][r].y + vc[r] - hV[r] + sK1[su][r].x);
          if (ilt) acc += N1e[r] * __expf(sK1[su][r + 1].y + vc[r] - N1v[r] + sK1[su][r + 1].x);
          e[r] = ok ? acc : 0.f;
        }
        if (k == 2 * LL && t == 191) e[3] = 1.f;
        // refills for step k-2
#pragma unroll
        for (int r = 0; r < 4; ++r) sVv[su][r] = V[iV + r];
#pragma unroll
        for (int r = 0; r < 4; ++r) sKt[su][r] = TA[iK + 1 + r].x;
#pragma unroll
        for (int r = 0; r < 5; ++r) sK1[su][r] = TA[iK1 + r];
        iV += dJd(sV_); --sV_;
        iK += dJd(sKc); --sKc;
        iK1 += dJd(sK1s); --sK1s;
        // E store (s = k-2), bf16, masked — separate buffer, no V aliasing
#pragma unroll
        for (int r = 0; r < 4; ++r)
          if ((unsigned)(d - r) <= 767u) Eo[iE + r] = __float2bfloat16(e[r]);
        iE += dJd(sE); --sE;
        RVb[k31 * 192 + t] = vc[0];
        REb[k31 * 192 + t] = e[0];
#pragma unroll
        for (int r = 0; r < 4; ++r) { N2v[r] = N1v[r]; N2e[r] = N1e[r]; }
        N1v[0] = vc[1]; N1e[0] = e[1];
        N1v[1] = vc[2]; N1e[1] = e[2];
        N1v[2] = vc[3]; N1e[2] = e[3];
#pragma unroll
        for (int r = 0; r < 4; ++r) { hV[r] = vc[r]; hE[r] = e[r]; }
        asm volatile("" ::: "memory");
      }
      if (l == 0 && w > 0)  lds_release_store(&Pb[w], kg - 7);
      if (l == 63 && w < 2) lds_release_store(&Cb[w], kg - 7);
    }
  }
}

}  // namespace

extern "C" void kernel_launch(void* const* d_in, const int* in_sizes, int n_in,
                              void* d_out, int out_size, void* d_ws, size_t ws_size,
                              hipStream_t stream) {
  const float* hx = (const float*)d_in[0];
  const float* hy = (const float*)d_in[1];
  const float* Wm = (const float*)d_in[2];
  const float* bm = (const float*)d_in[3];
  const float* Wg = (const float*)d_in[4];
  const float* bg = (const float*)d_in[5];

  float* aln   = (float*)d_out;
  float* theta = aln + (size_t)BB * L2E;
  float* A     = theta + (size_t)BB * L2E;

  // phase-2 workspace: packed (th,a) float2 diag + V (fp32) + E (bf16)
  float2* thaa = (float2*)d_ws;
  float*  Vd   = (float*)d_ws + (size_t)BB * L2E * 2;
  __hip_bfloat16* Ed = (__hip_bfloat16*)(Vd + (size_t)BB * L2E);
  // phase-1 workspace aliases the same region (dead after logits)
  float* zx = (float*)d_ws;
  float* zy = zx + (size_t)BB * LL * DD;
  float* gx = zy + (size_t)BB * LL * DD;
  float* gy = gx + (size_t)BB * LL * DD;

  linear_kernel<<<dim3(DD / 64, (BB * LL) / 64, 4), 256, 0, stream>>>(
      hx, hy, Wm, bm, Wg, bg, zx, zy, gx, gy);
  logits_kernel<<<dim3(LL / 64, LL / 64, BB * 2), 256, 0, stream>>>(
      zx, zy, gx, gy, theta, A);
  row2diag<<<dim3(LL / 64, LL / 64, BB), 256, 0, stream>>>(theta, A, thaa);

  const size_t SH = (size_t)(16 + 3 * 32 * 192) * sizeof(float);  // 73,792 B
  nw_fused<<<dim3(BB), 192, SH, stream>>>(thaa, Vd, Ed);

  diag2row<<<dim3(LL / 64, LL / 64, BB), 256, 0, stream>>>(Ed, aln);
}

// Round 9
// 2259.923 us; speedup vs baseline: 1.0658x; 1.0658x over previous
//
#include <hip/hip_runtime.h>
#include <hip/hip_bf16.h>
#include <math.h>

namespace {

constexpr int BB = 8;
constexpr int LL = 768;
constexpr int DD = 512;
constexpr int L2E = LL * LL;
constexpr float NEGF = -1e9f;

__device__ __forceinline__ float softplus_f(float x) {
  return x > 0.f ? x + log1pf(expf(-x)) : log1pf(expf(x));
}
__device__ __forceinline__ float logsigmoid_f(float x) {
  return x > 0.f ? -log1pf(expf(-x)) : x - log1pf(expf(x));
}

// diag-compact: diag s = r + c (0-based), element index Jext(s, r)
__device__ __forceinline__ int doffc(int s) {
  return (s <= LL - 1) ? ((s * (s + 1)) >> 1)
                       : (L2E - (((2 * LL - 1 - s) * (2 * LL - s)) >> 1));
}
__device__ __forceinline__ int Jext(int s, int r) {
  return doffc(s) + r - ((s > LL - 1) ? (s - (LL - 1)) : 0);
}
__device__ __forceinline__ int dJa(int s) { return (s <= LL - 2) ? s + 1 : 2 * LL - 2 - s; }
__device__ __forceinline__ int dJd(int s) { return (s <= LL - 1) ? -s : s - (2 * LL - 1); }

// -------- Kernel A: out[r][c] = sum_d X[r][d] * W[c][d] + bias[c] --------
__global__ __launch_bounds__(256) void linear_kernel(
    const float* __restrict__ hx, const float* __restrict__ hy,
    const float* __restrict__ Wm, const float* __restrict__ bm,
    const float* __restrict__ Wg, const float* __restrict__ bg,
    float* __restrict__ zx, float* __restrict__ zy,
    float* __restrict__ gx, float* __restrict__ gy) {
  constexpr int BK = 16;
  __shared__ float Xs[BK][64 + 1];
  __shared__ float Ws[BK][64 + 1];

  const int which = blockIdx.z;
  const float* Xin  = (which & 1) ? hy : hx;
  const float* W    = (which >= 2) ? Wg : Wm;
  const float* bias = (which >= 2) ? bg : bm;
  float* out = (which == 0) ? zx : (which == 1) ? zy : (which == 2) ? gx : gy;

  const int row0 = blockIdx.y * 64;
  const int col0 = blockIdx.x * 64;
  const int t  = threadIdx.x;
  const int tx = t & 15;
  const int ty = t >> 4;
  const int lrow = t >> 2;
  const int lseg = (t & 3) * 4;

  float acc[4][4] = {};
  for (int k0 = 0; k0 < DD; k0 += BK) {
    const float4 xv = *(const float4*)(Xin + (size_t)(row0 + lrow) * DD + k0 + lseg);
    const float4 wv = *(const float4*)(W   + (size_t)(col0 + lrow) * DD + k0 + lseg);
    Xs[lseg + 0][lrow] = xv.x; Xs[lseg + 1][lrow] = xv.y;
    Xs[lseg + 2][lrow] = xv.z; Xs[lseg + 3][lrow] = xv.w;
    Ws[lseg + 0][lrow] = wv.x; Ws[lseg + 1][lrow] = wv.y;
    Ws[lseg + 2][lrow] = wv.z; Ws[lseg + 3][lrow] = wv.w;
    __syncthreads();
#pragma unroll
    for (int kk = 0; kk < BK; ++kk) {
      float xr[4], wr[4];
#pragma unroll
      for (int a = 0; a < 4; ++a) xr[a] = Xs[kk][ty * 4 + a];
#pragma unroll
      for (int b = 0; b < 4; ++b) wr[b] = Ws[kk][tx * 4 + b];
#pragma unroll
      for (int a = 0; a < 4; ++a)
#pragma unroll
        for (int b = 0; b < 4; ++b) acc[a][b] += xr[a] * wr[b];
    }
    __syncthreads();
  }
#pragma unroll
  for (int a = 0; a < 4; ++a) {
    const int r = row0 + ty * 4 + a;
#pragma unroll
    for (int b2 = 0; b2 < 4; ++b2) {
      const int c = col0 + tx * 4 + b2;
      out[(size_t)r * DD + c] = acc[a][b2] + bias[c];
    }
  }
}

// -------- Kernel B: theta/A batched logits --------
__global__ __launch_bounds__(256) void logits_kernel(
    const float* __restrict__ zx, const float* __restrict__ zy,
    const float* __restrict__ gx, const float* __restrict__ gy,
    float* __restrict__ theta, float* __restrict__ Aout) {
  constexpr int BK = 16;
  __shared__ float Xs[BK][64 + 1];
  __shared__ float Ys[BK][64 + 1];

  const int bz = blockIdx.z;
  const int b = bz >> 1, w = bz & 1;
  const float* X = (w ? gx : zx) + (size_t)b * LL * DD;
  const float* Y = (w ? gy : zy) + (size_t)b * LL * DD;
  float* out = (w ? Aout : theta) + (size_t)b * L2E;

  const int row0 = blockIdx.y * 64;
  const int col0 = blockIdx.x * 64;
  const int t  = threadIdx.x;
  const int tx = t & 15;
  const int ty = t >> 4;
  const int lrow = t >> 2;
  const int lseg = (t & 3) * 4;

  float acc[4][4] = {};
  for (int k0 = 0; k0 < DD; k0 += BK) {
    const float4 xv = *(const float4*)(X + (size_t)(row0 + lrow) * DD + k0 + lseg);
    const float4 yv = *(const float4*)(Y + (size_t)(col0 + lrow) * DD + k0 + lseg);
    Xs[lseg + 0][lrow] = xv.x; Xs[lseg + 1][lrow] = xv.y;
    Xs[lseg + 2][lrow] = xv.z; Xs[lseg + 3][lrow] = xv.w;
    Ys[lseg + 0][lrow] = yv.x; Ys[lseg + 1][lrow] = yv.y;
    Ys[lseg + 2][lrow] = yv.z; Ys[lseg + 3][lrow] = yv.w;
    __syncthreads();
#pragma unroll
    for (int kk = 0; kk < BK; ++kk) {
      float xr[4], yr[4];
#pragma unroll
      for (int a = 0; a < 4; ++a) xr[a] = Xs[kk][ty * 4 + a];
#pragma unroll
      for (int b2 = 0; b2 < 4; ++b2) yr[b2] = Ys[kk][tx * 4 + b2];
#pragma unroll
      for (int a = 0; a < 4; ++a)
#pragma unroll
        for (int b2 = 0; b2 < 4; ++b2) acc[a][b2] += xr[a] * yr[b2];
    }
    __syncthreads();
  }
#pragma unroll
  for (int a = 0; a < 4; ++a) {
    const int r = row0 + ty * 4 + a;
#pragma unroll
    for (int b2 = 0; b2 < 4; ++b2) {
      const int c = col0 + tx * 4 + b2;
      const float v = acc[a][b2];
      out[(size_t)r * LL + c] = w ? logsigmoid_f(v) : softplus_f(v);
    }
  }
}

// -------- row-major theta,A -> packed diag-compact float2 (th, a) --------
__global__ __launch_bounds__(256) void row2diag(
    const float* __restrict__ theta, const float* __restrict__ A,
    float2* __restrict__ thaa) {
  __shared__ float tT[64 * 66];
  __shared__ float tA[64 * 66];
  const int b = blockIdx.z;
  const float* inT = theta + (size_t)b * L2E;
  const float* inA = A + (size_t)b * L2E;
  float2* out = thaa + (size_t)b * L2E;
  const int r0 = blockIdx.y * 64, c0 = blockIdx.x * 64;
  const int t = threadIdx.x, lane = t & 63, grp = t >> 6;
  for (int it = 0; it < 16; ++it) {
    const int rr = it * 4 + grp;
    tT[rr * 66 + lane] = inT[(size_t)(r0 + rr) * LL + c0 + lane];
    tA[rr * 66 + lane] = inA[(size_t)(r0 + rr) * LL + c0 + lane];
  }
  __syncthreads();
  for (int si = grp; si < 127; si += 4) {
    const int s = r0 + c0 + si;
    const int rlo = max(r0, s - c0 - 63);
    const int rhi = min(r0 + 63, s - c0);
    const int r = rlo + lane;
    if (r <= rhi) {
      const int ii = (r - r0) * 66 + (s - r - c0);
      out[doffc(s) + r - max(0, s - (LL - 1))] = make_float2(tT[ii], tA[ii]);
    }
  }
}

// -------- diag-compact bf16 E -> row-major fp32 (aln) --------
__global__ __launch_bounds__(256) void diag2row(
    const __hip_bfloat16* __restrict__ Ed, float* __restrict__ aln) {
  __shared__ float tile[64 * 66];
  const int b = blockIdx.z;
  const int r0 = blockIdx.y * 64;
  const int c0 = blockIdx.x * 64;
  const __hip_bfloat16* E = Ed + (size_t)b * L2E;
  float* out = aln + (size_t)b * L2E;
  const int t = threadIdx.x;
  const int lane = t & 63;
  const int grp = t >> 6;
  for (int si = grp; si < 127; si += 4) {
    const int s = r0 + c0 + si;
    const int rlo = max(r0, s - c0 - 63);
    const int rhi = min(r0 + 63, s - c0);
    const int r = rlo + lane;
    if (r <= rhi) {
      tile[(r - r0) * 66 + (s - r - c0)] =
          __bfloat162float(E[doffc(s) + r - max(0, s - (LL - 1))]);
    }
  }
  __syncthreads();
  for (int it = 0; it < 16; ++it) {
    const int rr = it * 4 + grp;
    out[(size_t)(r0 + rr) * LL + c0 + lane] = tile[rr * 66 + lane];
  }
}

// publish flag: LDS-only release (ring data is LDS; avoid vmcnt(0) drain)
__device__ __forceinline__ void lds_release_store(int* p, int v) {
  asm volatile("s_waitcnt lgkmcnt(0)" ::: "memory");
  __hip_atomic_store(p, v, __ATOMIC_RELAXED, __HIP_MEMORY_SCOPE_WORKGROUP);
}

// -------- NW forward: 4 rows/lane, 3 waves, depth-4 prefetch, 32-deep ring ----
__global__ __launch_bounds__(192, 1) void nw_fwd(
    const float2* __restrict__ thaa, float* __restrict__ Vd) {
  extern __shared__ float smf[];
  int* Pf = (int*)smf;          // [4] producer progress (last k published)
  int* Cf = (int*)smf + 4;      // [4] consumer progress (back-pressure)
  float* RVf = smf + 16;        // [32][192] V ring

  const int b = blockIdx.x;
  const float2* TA = thaa + (size_t)b * L2E;
  float* V = Vd + (size_t)b * L2E;

  const int t = threadIdx.x;
  const int w = t >> 6, l = t & 63;
  const int rowb = 4 * t;
  const int kb = 256 * w + 2;

  if (t < 4) { Pf[t] = 0; Cf[t] = 256 * t + 1; }
  __syncthreads();

  float2 pq[4][4];
  int sL = kb - 2, iL = Jext(sL, rowb);
#pragma unroll
  for (int du = 0; du < 4; ++du) {
    const int slot = (2 + du) & 3;
#pragma unroll
    for (int r = 0; r < 4; ++r) pq[slot][r] = TA[iL + r];
    iL += dJa(sL); ++sL;
  }
  int sS = kb - 2, iS = Jext(sS, rowb);
  float p1[4], p2[4];
#pragma unroll
  for (int r = 0; r < 4; ++r) { p1[r] = NEGF; p2[r] = NEGF; }
  float rvh = NEGF;
  const int rdT = (t == 0) ? 0 : (t - 1);

  for (int kg = kb; kg < kb + 1024; kg += 8) {
    if (l == 0 && w > 0 && kg < kb + 768) {
      const int need = min(kg + 6, kb + 766);
      while (__hip_atomic_load(&Pf[w - 1], __ATOMIC_ACQUIRE,
                               __HIP_MEMORY_SCOPE_WORKGROUP) < need) {}
    }
    if (l == 63 && w < 2) {  // back-pressure: don't overrun consumer by >24
      while (__hip_atomic_load(&Cf[w + 1], __ATOMIC_ACQUIRE,
                               __HIP_MEMORY_SCOPE_WORKGROUP) < kg - 24) {}
    }
#pragma unroll
    for (int u = 0; u < 8; ++u) {
      const int k = kg + u;
      const int su = (2 + u) & 3;  // k & 3 (kg ≡ 2 mod 8)
      const int k31 = k & 31, m31 = (k - 1) & 31;
      float rv = RVf[m31 * 192 + rdT];
      if (l == 0 && w == 0) rv = NEGF;
      float rdg = rvh;
      if (l == 0 && w == 0) rdg = (k == 2) ? 0.f : NEGF;
      const int d = k - rowb - 2;
      float vv[4];
#pragma unroll
      for (int r = 0; r < 4; ++r) {
        const float Vl = p1[r];
        const float Vu = (r == 0) ? rv : p1[r - 1];
        const float Vg = (r == 0) ? rdg : p2[r - 1];
        const float av = pq[su][r].y, tv = pq[su][r].x;
        const float lft = av + Vl, up = av + Vu;
        const float mx = fmaxf(Vg, fmaxf(lft, up));
        const float val = tv + mx +
            __logf(__expf(Vg - mx) + __expf(lft - mx) + __expf(up - mx));
        vv[r] = ((unsigned)(d - r) <= 767u) ? val : NEGF;
      }
#pragma unroll
      for (int r = 0; r < 4; ++r) pq[su][r] = TA[iL + r];  // for step k+4
      iL += dJa(sL); ++sL;
#pragma unroll
      for (int r = 0; r < 4; ++r)
        if ((unsigned)(d - r) <= 767u) V[iS + r] = vv[r];
      iS += dJa(sS); ++sS;
      RVf[k31 * 192 + t] = vv[3];
      rvh = rv;
#pragma unroll
      for (int r = 0; r < 4; ++r) { p2[r] = p1[r]; p1[r] = vv[r]; }
      asm volatile("" ::: "memory");
    }
    if (l == 63 && w < 2) lds_release_store(&Pf[w], kg + 7);
    if (l == 0 && w > 0)  lds_release_store(&Cf[w], kg + 7);
  }
}

// -------- NW backward: depth-4 prefetch, no V-alias (bf16 E), sKt capture ----
__global__ __launch_bounds__(192, 1) void nw_bwd(
    const float2* __restrict__ thaa, const float* __restrict__ Vd,
    __hip_bfloat16* __restrict__ Ed) {
  extern __shared__ float smf[];
  int* Pb = (int*)smf;          // [4] producer progress (descending)
  int* Cb = (int*)smf + 4;      // [4] consumer progress (back-pressure)
  float* RVb = smf + 16;        // [32][192]
  float* REb = RVb + 32 * 192;  // [32][192]

  const int b = blockIdx.x;
  const float2* TA = thaa + (size_t)b * L2E;
  const float* V = Vd + (size_t)b * L2E;
  __hip_bfloat16* Eo = Ed + (size_t)b * L2E;

  const int t = threadIdx.x;
  const int w = t >> 6, l = t & 63;
  const int rowb = 4 * t;
  const int kb = 256 * w + 2;
  const int ke = kb + 1023;

  if (t < 4) { Pb[t] = 0x7fffffff; Cb[t] = 256 * t + 1026; }
  __syncthreads();

  float sVv[4][4];    // V at s=k-2, rows rowb..rowb+3
  float2 sK1[4][5];   // (th, a) at s=k-1, rows rowb..rowb+4
  int sV_ = ke - 2, iV = Jext(sV_, rowb);
  int sK1s = ke - 1, iK1 = Jext(sK1s, rowb);
#pragma unroll
  for (int du = 0; du < 4; ++du) {
    const int slot = (1 - du) & 3;
#pragma unroll
    for (int r = 0; r < 4; ++r) sVv[slot][r] = V[iV + r];
#pragma unroll
    for (int r = 0; r < 5; ++r) sK1[slot][r] = TA[iK1 + r];
    iV += dJd(sV_); --sV_;
    iK1 += dJd(sK1s); --sK1s;
  }
  // sKt register pipeline: th at s=k, rows rowb+1..rowb+4. Captured each step
  // from sK1 (which holds s=k-1 when processing step k) BEFORE the refill.
  float sKtb[2][4];
  {
    const int j0 = Jext(ke, rowb);
#pragma unroll
    for (int r = 0; r < 4; ++r) sKtb[0][r] = TA[j0 + 1 + r].x;
  }
  int sE = ke - 2, iE = Jext(sE, rowb);
  float N1v[4], N1e[4], N2v[4], N2e[4], hV[4], hE[4];
#pragma unroll
  for (int r = 0; r < 4; ++r) {
    N1v[r] = 0.f; N1e[r] = 0.f; N2v[r] = 0.f; N2e[r] = 0.f; hV[r] = 0.f; hE[r] = 0.f;
  }
  const int rdU = (t == 191) ? 191 : (t + 1);

  for (int kg = ke; kg > ke - 1024; kg -= 8) {
    if (l == 63 && w < 2 && kg >= kb + 255) {
      const int need = max(kg - 6, kb + 256);
      while (__hip_atomic_load(&Pb[w + 1], __ATOMIC_ACQUIRE,
                               __HIP_MEMORY_SCOPE_WORKGROUP) > need) {}
    }
    if (l == 0 && w > 0) {  // back-pressure vs consumer below
      while (__hip_atomic_load(&Cb[w - 1], __ATOMIC_ACQUIRE,
                               __HIP_MEMORY_SCOPE_WORKGROUP) > kg + 23) {}
    }
#pragma unroll
    for (int u = 0; u < 8; ++u) {
      const int k = kg - u;
      const int su = (1 - u) & 3;   // k & 3 (kg ≡ 1 mod 8)
      const int k31 = k & 31, p31 = (k + 1) & 31;
      const int cb = u & 1, nb = (u + 1) & 1;  // sKt pipeline slots (static)
      N1v[3] = RVb[p31 * 192 + rdU];
      N1e[3] = REb[p31 * 192 + rdU];
      const int d = k - rowb - 2;
      float e[4], vc[4];
#pragma unroll
      for (int r = 0; r < 4; ++r) {
        vc[r] = sVv[su][r];
        const bool ok  = (unsigned)(d - r) <= 767u;
        const bool jlt = (d - r) < 767;
        const bool ilt = (rowb + r) < 767;
        float acc = 0.f;
        if (ilt && jlt) acc += N2e[r] * __expf(vc[r] - N2v[r] + sKtb[cb][r]);
        if (jlt) acc += hE[r] * __expf(sK1[su][r].y + vc[r] - hV[r] + sK1[su][r].x);
        if (ilt) acc += N1e[r] * __expf(sK1[su][r + 1].y + vc[r] - N1v[r] + sK1[su][r + 1].x);
        e[r] = ok ? acc : 0.f;
      }
      if (k == 2 * LL && t == 191) e[3] = 1.f;
      // capture th(s=k-1, rows rowb+1..rowb+4) for step k-1 — BEFORE refill
#pragma unroll
      for (int r = 0; r < 4; ++r) sKtb[nb][r] = sK1[su][r + 1].x;
      // refills for step k-4
#pragma unroll
      for (int r = 0; r < 4; ++r) sVv[su][r] = V[iV + r];
#pragma unroll
      for (int r = 0; r < 5; ++r) sK1[su][r] = TA[iK1 + r];
      iV += dJd(sV_); --sV_;
      iK1 += dJd(sK1s); --sK1s;
      // E store (s = k-2), bf16, separate buffer — no V aliasing
#pragma unroll
      for (int r = 0; r < 4; ++r)
        if ((unsigned)(d - r) <= 767u) Eo[iE + r] = __float2bfloat16(e[r]);
      iE += dJd(sE); --sE;
      RVb[k31 * 192 + t] = vc[0];
      REb[k31 * 192 + t] = e[0];
#pragma unroll
      for (int r = 0; r < 4; ++r) { N2v[r] = N1v[r]; N2e[r] = N1e[r]; }
      N1v[0] = vc[1]; N1e[0] = e[1];
      N1v[1] = vc[2]; N1e[1] = e[2];
      N1v[2] = vc[3]; N1e[2] = e[3];
#pragma unroll
      for (int r = 0; r < 4; ++r) { hV[r] = vc[r]; hE[r] = e[r]; }
      asm volatile("" ::: "memory");
    }
    if (l == 0 && w > 0)  lds_release_store(&Pb[w], kg - 7);
    if (l == 63 && w < 2) lds_release_store(&Cb[w], kg - 7);
  }
}

}  // namespace

extern "C" void kernel_launch(void* const* d_in, const int* in_sizes, int n_in,
                              void* d_out, int out_size, void* d_ws, size_t ws_size,
                              hipStream_t stream) {
  const float* hx = (const float*)d_in[0];
  const float* hy = (const float*)d_in[1];
  const float* Wm = (const float*)d_in[2];
  const float* bm = (const float*)d_in[3];
  const float* Wg = (const float*)d_in[4];
  const float* bg = (const float*)d_in[5];

  float* aln   = (float*)d_out;
  float* theta = aln + (size_t)BB * L2E;
  float* A     = theta + (size_t)BB * L2E;

  // phase-2 workspace: packed (th,a) float2 diag + V (fp32) + E (bf16)
  float2* thaa = (float2*)d_ws;
  float*  Vd   = (float*)d_ws + (size_t)BB * L2E * 2;
  __hip_bfloat16* Ed = (__hip_bfloat16*)(Vd + (size_t)BB * L2E);
  // phase-1 workspace aliases the same region (dead after logits)
  float* zx = (float*)d_ws;
  float* zy = zx + (size_t)BB * LL * DD;
  float* gx = zy + (size_t)BB * LL * DD;
  float* gy = gx + (size_t)BB * LL * DD;

  linear_kernel<<<dim3(DD / 64, (BB * LL) / 64, 4), 256, 0, stream>>>(
      hx, hy, Wm, bm, Wg, bg, zx, zy, gx, gy);
  logits_kernel<<<dim3(LL / 64, LL / 64, BB * 2), 256, 0, stream>>>(
      zx, zy, gx, gy, theta, A);
  row2diag<<<dim3(LL / 64, LL / 64, BB), 256, 0, stream>>>(theta, A, thaa);

  const size_t SHF = (size_t)(16 + 32 * 192) * sizeof(float);      // 24,640 B
  const size_t SHB = (size_t)(16 + 2 * 32 * 192) * sizeof(float);  // 49,216 B
  nw_fwd<<<dim3(BB), 192, SHF, stream>>>(thaa, Vd);
  nw_bwd<<<dim3(BB), 192, SHB, stream>>>(thaa, Vd, Ed);

  diag2row<<<dim3(LL / 64, LL / 64, BB), 256, 0, stream>>>(Ed, aln);
}

// Round 10
// 2217.624 us; speedup vs baseline: 1.0862x; 1.0191x over previous
//
#include <hip/hip_runtime.h>
#include <hip/hip_bf16.h>
#include <math.h>

namespace {

constexpr int BB = 8;
constexpr int LL = 768;
constexpr int DD = 512;
constexpr int L2E = LL * LL;
constexpr float NEGF = -1e9f;

__device__ __forceinline__ float softplus_f(float x) {
  return x > 0.f ? x + log1pf(expf(-x)) : log1pf(expf(x));
}
__device__ __forceinline__ float logsigmoid_f(float x) {
  return x > 0.f ? -log1pf(expf(-x)) : x - log1pf(expf(x));
}

// packed bf16x2: low 16 = theta, high 16 = A
__device__ __forceinline__ float bf_lo(unsigned u) { return __uint_as_float(u << 16); }
__device__ __forceinline__ float bf_hi(unsigned u) { return __uint_as_float(u & 0xffff0000u); }

// diag-compact: diag s = r + c (0-based), element index Jext(s, r)
__device__ __forceinline__ int doffc(int s) {
  return (s <= LL - 1) ? ((s * (s + 1)) >> 1)
                       : (L2E - (((2 * LL - 1 - s) * (2 * LL - s)) >> 1));
}
__device__ __forceinline__ int Jext(int s, int r) {
  return doffc(s) + r - ((s > LL - 1) ? (s - (LL - 1)) : 0);
}
__device__ __forceinline__ int dJa(int s) { return (s <= LL - 2) ? s + 1 : 2 * LL - 2 - s; }
__device__ __forceinline__ int dJd(int s) { return (s <= LL - 1) ? -s : s - (2 * LL - 1); }

// -------- Kernel A: out[r][c] = sum_d X[r][d] * W[c][d] + bias[c] --------
__global__ __launch_bounds__(256) void linear_kernel(
    const float* __restrict__ hx, const float* __restrict__ hy,
    const float* __restrict__ Wm, const float* __restrict__ bm,
    const float* __restrict__ Wg, const float* __restrict__ bg,
    float* __restrict__ zx, float* __restrict__ zy,
    float* __restrict__ gx, float* __restrict__ gy) {
  constexpr int BK = 16;
  __shared__ float Xs[BK][64 + 1];
  __shared__ float Ws[BK][64 + 1];

  const int which = blockIdx.z;
  const float* Xin  = (which & 1) ? hy : hx;
  const float* W    = (which >= 2) ? Wg : Wm;
  const float* bias = (which >= 2) ? bg : bm;
  float* out = (which == 0) ? zx : (which == 1) ? zy : (which == 2) ? gx : gy;

  const int row0 = blockIdx.y * 64;
  const int col0 = blockIdx.x * 64;
  const int t  = threadIdx.x;
  const int tx = t & 15;
  const int ty = t >> 4;
  const int lrow = t >> 2;
  const int lseg = (t & 3) * 4;

  float acc[4][4] = {};
  for (int k0 = 0; k0 < DD; k0 += BK) {
    const float4 xv = *(const float4*)(Xin + (size_t)(row0 + lrow) * DD + k0 + lseg);
    const float4 wv = *(const float4*)(W   + (size_t)(col0 + lrow) * DD + k0 + lseg);
    Xs[lseg + 0][lrow] = xv.x; Xs[lseg + 1][lrow] = xv.y;
    Xs[lseg + 2][lrow] = xv.z; Xs[lseg + 3][lrow] = xv.w;
    Ws[lseg + 0][lrow] = wv.x; Ws[lseg + 1][lrow] = wv.y;
    Ws[lseg + 2][lrow] = wv.z; Ws[lseg + 3][lrow] = wv.w;
    __syncthreads();
#pragma unroll
    for (int kk = 0; kk < BK; ++kk) {
      float xr[4], wr[4];
#pragma unroll
      for (int a = 0; a < 4; ++a) xr[a] = Xs[kk][ty * 4 + a];
#pragma unroll
      for (int b = 0; b < 4; ++b) wr[b] = Ws[kk][tx * 4 + b];
#pragma unroll
      for (int a = 0; a < 4; ++a)
#pragma unroll
        for (int b = 0; b < 4; ++b) acc[a][b] += xr[a] * wr[b];
    }
    __syncthreads();
  }
#pragma unroll
  for (int a = 0; a < 4; ++a) {
    const int r = row0 + ty * 4 + a;
#pragma unroll
    for (int b2 = 0; b2 < 4; ++b2) {
      const int c = col0 + tx * 4 + b2;
      out[(size_t)r * DD + c] = acc[a][b2] + bias[c];
    }
  }
}

// -------- Kernel B: theta/A batched logits --------
__global__ __launch_bounds__(256) void logits_kernel(
    const float* __restrict__ zx, const float* __restrict__ zy,
    const float* __restrict__ gx, const float* __restrict__ gy,
    float* __restrict__ theta, float* __restrict__ Aout) {
  constexpr int BK = 16;
  __shared__ float Xs[BK][64 + 1];
  __shared__ float Ys[BK][64 + 1];

  const int bz = blockIdx.z;
  const int b = bz >> 1, w = bz & 1;
  const float* X = (w ? gx : zx) + (size_t)b * LL * DD;
  const float* Y = (w ? gy : zy) + (size_t)b * LL * DD;
  float* out = (w ? Aout : theta) + (size_t)b * L2E;

  const int row0 = blockIdx.y * 64;
  const int col0 = blockIdx.x * 64;
  const int t  = threadIdx.x;
  const int tx = t & 15;
  const int ty = t >> 4;
  const int lrow = t >> 2;
  const int lseg = (t & 3) * 4;

  float acc[4][4] = {};
  for (int k0 = 0; k0 < DD; k0 += BK) {
    const float4 xv = *(const float4*)(X + (size_t)(row0 + lrow) * DD + k0 + lseg);
    const float4 yv = *(const float4*)(Y + (size_t)(col0 + lrow) * DD + k0 + lseg);
    Xs[lseg + 0][lrow] = xv.x; Xs[lseg + 1][lrow] = xv.y;
    Xs[lseg + 2][lrow] = xv.z; Xs[lseg + 3][lrow] = xv.w;
    Ys[lseg + 0][lrow] = yv.x; Ys[lseg + 1][lrow] = yv.y;
    Ys[lseg + 2][lrow] = yv.z; Ys[lseg + 3][lrow] = yv.w;
    __syncthreads();
#pragma unroll
    for (int kk = 0; kk < BK; ++kk) {
      float xr[4], yr[4];
#pragma unroll
      for (int a = 0; a < 4; ++a) xr[a] = Xs[kk][ty * 4 + a];
#pragma unroll
      for (int b2 = 0; b2 < 4; ++b2) yr[b2] = Ys[kk][tx * 4 + b2];
#pragma unroll
      for (int a = 0; a < 4; ++a)
#pragma unroll
        for (int b2 = 0; b2 < 4; ++b2) acc[a][b2] += xr[a] * yr[b2];
    }
    __syncthreads();
  }
#pragma unroll
  for (int a = 0; a < 4; ++a) {
    const int r = row0 + ty * 4 + a;
#pragma unroll
    for (int b2 = 0; b2 < 4; ++b2) {
      const int c = col0 + tx * 4 + b2;
      const float v = acc[a][b2];
      out[(size_t)r * LL + c] = w ? logsigmoid_f(v) : softplus_f(v);
    }
  }
}

// -------- row-major theta,A -> packed diag-compact bf16x2 --------
__global__ __launch_bounds__(256) void row2diag(
    const float* __restrict__ theta, const float* __restrict__ A,
    unsigned* __restrict__ thaa) {
  __shared__ float tT[64 * 66];
  __shared__ float tA[64 * 66];
  const int b = blockIdx.z;
  const float* inT = theta + (size_t)b * L2E;
  const float* inA = A + (size_t)b * L2E;
  unsigned* out = thaa + (size_t)b * L2E;
  const int r0 = blockIdx.y * 64, c0 = blockIdx.x * 64;
  const int t = threadIdx.x, lane = t & 63, grp = t >> 6;
  for (int it = 0; it < 16; ++it) {
    const int rr = it * 4 + grp;
    tT[rr * 66 + lane] = inT[(size_t)(r0 + rr) * LL + c0 + lane];
    tA[rr * 66 + lane] = inA[(size_t)(r0 + rr) * LL + c0 + lane];
  }
  __syncthreads();
  for (int si = grp; si < 127; si += 4) {
    const int s = r0 + c0 + si;
    const int rlo = max(r0, s - c0 - 63);
    const int rhi = min(r0 + 63, s - c0);
    const int r = rlo + lane;
    if (r <= rhi) {
      const int ii = (r - r0) * 66 + (s - r - c0);
      const unsigned ut = __bfloat16_as_ushort(__float2bfloat16(tT[ii]));
      const unsigned ua = __bfloat16_as_ushort(__float2bfloat16(tA[ii]));
      out[doffc(s) + r - max(0, s - (LL - 1))] = (ua << 16) | ut;
    }
  }
}

// -------- diag-compact bf16 E -> row-major fp32 (aln) --------
__global__ __launch_bounds__(256) void diag2row(
    const __hip_bfloat16* __restrict__ Ed, float* __restrict__ aln) {
  __shared__ float tile[64 * 66];
  const int b = blockIdx.z;
  const int r0 = blockIdx.y * 64;
  const int c0 = blockIdx.x * 64;
  const __hip_bfloat16* E = Ed + (size_t)b * L2E;
  float* out = aln + (size_t)b * L2E;
  const int t = threadIdx.x;
  const int lane = t & 63;
  const int grp = t >> 6;
  for (int si = grp; si < 127; si += 4) {
    const int s = r0 + c0 + si;
    const int rlo = max(r0, s - c0 - 63);
    const int rhi = min(r0 + 63, s - c0);
    const int r = rlo + lane;
    if (r <= rhi) {
      tile[(r - r0) * 66 + (s - r - c0)] =
          __bfloat162float(E[doffc(s) + r - max(0, s - (LL - 1))]);
    }
  }
  __syncthreads();
  for (int it = 0; it < 16; ++it) {
    const int rr = it * 4 + grp;
    out[(size_t)(r0 + rr) * LL + c0 + lane] = tile[rr * 66 + lane];
  }
}

// publish flag: LDS-only release (ring data is LDS; avoid vmcnt(0) drain)
__device__ __forceinline__ void lds_release_store(int* p, int v) {
  asm volatile("s_waitcnt lgkmcnt(0)" ::: "memory");
  __hip_atomic_store(p, v, __ATOMIC_RELAXED, __HIP_MEMORY_SCOPE_WORKGROUP);
}

// -------- NW forward: shfl cross-lane, LDS only at 2 wave boundaries --------
__global__ __launch_bounds__(192, 1) void nw_fwd(
    const unsigned* __restrict__ thaa, float* __restrict__ Vd) {
  __shared__ int Pf[4];
  __shared__ float BvF[2][1024];  // full-history boundary stream (row 256(w+1))

  const int b = blockIdx.x;
  const unsigned* TA = thaa + (size_t)b * L2E;
  float* V = Vd + (size_t)b * L2E;

  const int t = threadIdx.x;
  const int w = t >> 6, l = t & 63;
  const int rowb = 4 * t;
  const int kb = 256 * w + 2;

  if (t < 4) Pf[t] = 0;
  __syncthreads();

  unsigned pq[4][4];
  int sL = kb - 2, iL = Jext(sL, rowb);
#pragma unroll
  for (int du = 0; du < 4; ++du) {
    const int slot = (2 + du) & 3;
#pragma unroll
    for (int r = 0; r < 4; ++r) pq[slot][r] = TA[iL + r];
    iL += dJa(sL); ++sL;
  }
  int sS = kb - 2, iS = Jext(sS, rowb);
  float p1[4], p2[4];
#pragma unroll
  for (int r = 0; r < 4; ++r) { p1[r] = NEGF; p2[r] = NEGF; }
  float rvh = NEGF;   // row 4t at diag k-2 (prev step's rv)
  float pv3 = NEGF;   // own vv[3] of previous step (shfl source)

  for (int kg = kb; kg < kb + 1024; kg += 8) {
    if (l == 0 && w > 0 && kg < kb + 768) {
      const int need = min(kg + 6, kb + 766);
      while (__hip_atomic_load(&Pf[w - 1], __ATOMIC_ACQUIRE,
                               __HIP_MEMORY_SCOPE_WORKGROUP) < need) {}
    }
#pragma unroll
    for (int u = 0; u < 8; ++u) {
      const int k = kg + u;
      const int su = (2 + u) & 3;  // k & 3 (kb ≡ 2 mod 4)
      // cross-lane: row 4t at diag k-1
      float rv = __shfl_up(pv3, 1);
      if (l == 0) {
        if (w == 0) rv = NEGF;
        else rv = BvF[w - 1][min(k - kb + 255, 1023)];
      }
      float rdg = rvh;
      if (l == 0 && w == 0) rdg = (k == 2) ? 0.f : NEGF;
      const int d = k - rowb - 2;
      float vv[4];
#pragma unroll
      for (int r = 0; r < 4; ++r) {
        const float Vl = p1[r];
        const float Vu = (r == 0) ? rv : p1[r - 1];
        const float Vg = (r == 0) ? rdg : p2[r - 1];
        const float av = bf_hi(pq[su][r]), tv = bf_lo(pq[su][r]);
        const float lft = av + Vl, up = av + Vu;
        const float mx = fmaxf(Vg, fmaxf(lft, up));
        const float val = tv + mx +
            __logf(__expf(Vg - mx) + __expf(lft - mx) + __expf(up - mx));
        vv[r] = ((unsigned)(d - r) <= 767u) ? val : NEGF;
      }
#pragma unroll
      for (int r = 0; r < 4; ++r) pq[su][r] = TA[iL + r];  // for step k+4
      iL += dJa(sL); ++sL;
#pragma unroll
      for (int r = 0; r < 4; ++r)
        if ((unsigned)(d - r) <= 767u) V[iS + r] = vv[r];
      iS += dJa(sS); ++sS;
      if (l == 63 && w < 2) BvF[w][k - kb] = vv[3];
      pv3 = vv[3];
      rvh = rv;
#pragma unroll
      for (int r = 0; r < 4; ++r) { p2[r] = p1[r]; p1[r] = vv[r]; }
    }
    if (l == 63 && w < 2) lds_release_store(&Pf[w], kg + 7);
  }
}

// -------- NW backward: shfl cross-lane, boundary streams, bf16 E out --------
__global__ __launch_bounds__(192, 1) void nw_bwd(
    const unsigned* __restrict__ thaa, const float* __restrict__ Vd,
    __hip_bfloat16* __restrict__ Ed) {
  __shared__ int Pb[4];
  __shared__ float Bv2[2][1024];  // boundary V stream (row 256w+1 of wave w+1)
  __shared__ float Be2[2][1024];  // boundary E stream

  const int b = blockIdx.x;
  const unsigned* TA = thaa + (size_t)b * L2E;
  const float* V = Vd + (size_t)b * L2E;
  __hip_bfloat16* Eo = Ed + (size_t)b * L2E;

  const int t = threadIdx.x;
  const int w = t >> 6, l = t & 63;
  const int rowb = 4 * t;
  const int kb = 256 * w + 2;
  const int ke = kb + 1023;

  if (t < 4) Pb[t] = 0x7fffffff;
  __syncthreads();

  float sVv[4][4];      // V at s=k-2, rows rowb..rowb+3
  unsigned sK1[4][5];   // packed (th,a) at s=k-1, rows rowb..rowb+4
  int sV_ = ke - 2, iV = Jext(sV_, rowb);
  int sK1s = ke - 1, iK1 = Jext(sK1s, rowb);
#pragma unroll
  for (int du = 0; du < 4; ++du) {
    const int slot = (1 - du) & 3;
#pragma unroll
    for (int r = 0; r < 4; ++r) sVv[slot][r] = V[iV + r];
#pragma unroll
    for (int r = 0; r < 5; ++r) sK1[slot][r] = TA[iK1 + r];
    iV += dJd(sV_); --sV_;
    iK1 += dJd(sK1s); --sK1s;
  }
  // sKt pipeline: th at s=k, rows rowb+1..rowb+4; captured from sK1 pre-refill
  float sKtb[2][4];
  {
    const int j0 = Jext(ke, rowb);
#pragma unroll
    for (int r = 0; r < 4; ++r) sKtb[0][r] = bf_lo(TA[j0 + 1 + r]);
  }
  int sE = ke - 2, iE = Jext(sE, rowb);
  float N1v[4], N1e[4], N2v[4], N2e[4], hV[4], hE[4];
#pragma unroll
  for (int r = 0; r < 4; ++r) {
    N1v[r] = 0.f; N1e[r] = 0.f; N2v[r] = 0.f; N2e[r] = 0.f; hV[r] = 0.f; hE[r] = 0.f;
  }
  float pv0 = 0.f, pe0 = 0.f;  // own (vc[0], e[0]) of previous step (shfl source)

  for (int kg = ke; kg > ke - 1024; kg -= 8) {
    if (l == 63 && w < 2 && kg >= kb + 255) {
      const int need = max(kg - 6, kb + 256);
      while (__hip_atomic_load(&Pb[w + 1], __ATOMIC_ACQUIRE,
                               __HIP_MEMORY_SCOPE_WORKGROUP) > need) {}
    }
#pragma unroll
    for (int u = 0; u < 8; ++u) {
      const int k = kg - u;
      const int su = (1 - u) & 3;   // k & 3 (ke ≡ 1 mod 4)
      const int cb = u & 1, nb = (u + 1) & 1;
      // cross-lane: row 4t+5 (= lane t+1's row 0) at diag k+1
      N1v[3] = __shfl_down(pv0, 1);
      N1e[3] = __shfl_down(pe0, 1);
      if (l == 63) {
        if (w < 2) {
          const int bi = min(ke - k + 255, 1023);
          N1v[3] = Bv2[w][bi];
          N1e[3] = Be2[w][bi];
        } else {
          N1v[3] = 0.f; N1e[3] = 0.f;
        }
      }
      const int d = k - rowb - 2;
      float e[4], vc[4];
#pragma unroll
      for (int r = 0; r < 4; ++r) {
        vc[r] = sVv[su][r];
        const bool ok  = (unsigned)(d - r) <= 767u;
        const bool jlt = (d - r) < 767;
        const bool ilt = (rowb + r) < 767;
        float acc = 0.f;
        if (ilt && jlt) acc += N2e[r] * __expf(vc[r] - N2v[r] + sKtb[cb][r]);
        if (jlt) acc += hE[r] * __expf(bf_hi(sK1[su][r]) + vc[r] - hV[r] + bf_lo(sK1[su][r]));
        if (ilt) acc += N1e[r] * __expf(bf_hi(sK1[su][r + 1]) + vc[r] - N1v[r] + bf_lo(sK1[su][r + 1]));
        e[r] = ok ? acc : 0.f;
      }
      if (k == 2 * LL && t == 191) e[3] = 1.f;
      // capture th(s=k-1, rows rowb+1..rowb+4) for step k-1 — BEFORE refill
#pragma unroll
      for (int r = 0; r < 4; ++r) sKtb[nb][r] = bf_lo(sK1[su][r + 1]);
      // refills for step k-4
#pragma unroll
      for (int r = 0; r < 4; ++r) sVv[su][r] = V[iV + r];
#pragma unroll
      for (int r = 0; r < 5; ++r) sK1[su][r] = TA[iK1 + r];
      iV += dJd(sV_); --sV_;
      iK1 += dJd(sK1s); --sK1s;
      // E store (s = k-2), bf16
#pragma unroll
      for (int r = 0; r < 4; ++r)
        if ((unsigned)(d - r) <= 767u) Eo[iE + r] = __float2bfloat16(e[r]);
      iE += dJd(sE); --sE;
      // boundary publish: own row 0 (= row 256w+1) values for wave w-1
      if (l == 0 && w > 0) {
        Bv2[w - 1][ke - k] = vc[0];
        Be2[w - 1][ke - k] = e[0];
      }
      pv0 = vc[0];
      pe0 = e[0];
#pragma unroll
      for (int r = 0; r < 4; ++r) { N2v[r] = N1v[r]; N2e[r] = N1e[r]; }
      N1v[0] = vc[1]; N1e[0] = e[1];
      N1v[1] = vc[2]; N1e[1] = e[2];
      N1v[2] = vc[3]; N1e[2] = e[3];
#pragma unroll
      for (int r = 0; r < 4; ++r) { hV[r] = vc[r]; hE[r] = e[r]; }
    }
    if (l == 0 && w > 0) lds_release_store(&Pb[w], kg - 7);
  }
}

}  // namespace

extern "C" void kernel_launch(void* const* d_in, const int* in_sizes, int n_in,
                              void* d_out, int out_size, void* d_ws, size_t ws_size,
                              hipStream_t stream) {
  const float* hx = (const float*)d_in[0];
  const float* hy = (const float*)d_in[1];
  const float* Wm = (const float*)d_in[2];
  const float* bm = (const float*)d_in[3];
  const float* Wg = (const float*)d_in[4];
  const float* bg = (const float*)d_in[5];

  float* aln   = (float*)d_out;
  float* theta = aln + (size_t)BB * L2E;
  float* A     = theta + (size_t)BB * L2E;

  // phase-2 workspace: packed bf16x2 (th,a) diag + V (fp32) + E (bf16)
  unsigned* thaa = (unsigned*)d_ws;
  float* Vd = (float*)d_ws + (size_t)BB * L2E;
  __hip_bfloat16* Ed = (__hip_bfloat16*)(Vd + (size_t)BB * L2E);
  // phase-1 workspace aliases the same region (dead after logits)
  float* zx = (float*)d_ws;
  float* zy = zx + (size_t)BB * LL * DD;
  float* gx = zy + (size_t)BB * LL * DD;
  float* gy = gx + (size_t)BB * LL * DD;

  linear_kernel<<<dim3(DD / 64, (BB * LL) / 64, 4), 256, 0, stream>>>(
      hx, hy, Wm, bm, Wg, bg, zx, zy, gx, gy);
  logits_kernel<<<dim3(LL / 64, LL / 64, BB * 2), 256, 0, stream>>>(
      zx, zy, gx, gy, theta, A);
  row2diag<<<dim3(LL / 64, LL / 64, BB), 256, 0, stream>>>(theta, A, thaa);

  nw_fwd<<<dim3(BB), 192, 0, stream>>>(thaa, Vd);
  nw_bwd<<<dim3(BB), 192, 0, stream>>>(thaa, Vd, Ed);

  diag2row<<<dim3(LL / 64, LL / 64, BB), 256, 0, stream>>>(Ed, aln);
}

// Round 11
// 2014.694 us; speedup vs baseline: 1.1956x; 1.1007x over previous
//
#include <hip/hip_runtime.h>
#include <hip/hip_bf16.h>
#include <math.h>

namespace {

constexpr int BB = 8;
constexpr int LL = 768;
constexpr int DD = 512;
constexpr int L2E = LL * LL;
constexpr int LDIAG = L2E + 8192;  // padded compact-aligned diag layout stride
constexpr float NEGF = -1e9f;

__device__ __forceinline__ float softplus_f(float x) {
  return x > 0.f ? x + log1pf(expf(-x)) : log1pf(expf(x));
}
__device__ __forceinline__ float logsigmoid_f(float x) {
  return x > 0.f ? -log1pf(expf(-x)) : x - log1pf(expf(x));
}

// packed bf16x2: low 16 = theta, high 16 = A
__device__ __forceinline__ float bf_lo(unsigned u) { return __uint_as_float(u << 16); }
__device__ __forceinline__ float bf_hi(unsigned u) { return __uint_as_float(u & 0xffff0000u); }

__device__ __forceinline__ int lofs(int s) { return (s > LL - 1) ? (s - (LL - 1)) : 0; }

// Alignment-corrected compact diag layout: slot s data starts at Dmap(s),
// Dmap(s) == lofs(s) (mod 4), inter-slot gaps in [3,6]. Derived for LL=768.
__device__ __forceinline__ int Dmap(int s) {
  if (s <= LL - 1) {
    const int m = s >> 2, i = s & 3;
    const int c = (i == 0) ? 4 : (i == 1) ? 8 : (i == 2) ? 16 : 24;
    return 8 * m * m + (20 + 4 * i) * m + c;
  }
  const int q = (s - LL) >> 2, i = (s - LL) & 3;
  const int base = 298757 + 3092 * q - 8 * q * q;
  const int off = (i == 0) ? 0 : (i == 1) ? (773 - 4 * q)
                : (i == 2) ? (1546 - 8 * q) : (2315 - 12 * q);
  return base + off;
}
__device__ __forceinline__ int dDa(int s) {  // Dmap(s+1) - Dmap(s)
  if (s < LL - 1) return s + 4 + ((-s) & 3);
  if (s == LL - 1) return 773;
  return 1539 - s + ((s + 2) & 3);
}
// per-lane stream index delta ascending (includes lo shift)
__device__ __forceinline__ int dIa(int s) { return dDa(s) - ((s >= LL - 1) ? 1 : 0); }

// -------- Kernel A: out[r][c] = sum_d X[r][d] * W[c][d] + bias[c] --------
__global__ __launch_bounds__(256) void linear_kernel(
    const float* __restrict__ hx, const float* __restrict__ hy,
    const float* __restrict__ Wm, const float* __restrict__ bm,
    const float* __restrict__ Wg, const float* __restrict__ bg,
    float* __restrict__ zx, float* __restrict__ zy,
    float* __restrict__ gx, float* __restrict__ gy) {
  constexpr int BK = 16;
  __shared__ float Xs[BK][64 + 1];
  __shared__ float Ws[BK][64 + 1];

  const int which = blockIdx.z;
  const float* Xin  = (which & 1) ? hy : hx;
  const float* W    = (which >= 2) ? Wg : Wm;
  const float* bias = (which >= 2) ? bg : bm;
  float* out = (which == 0) ? zx : (which == 1) ? zy : (which == 2) ? gx : gy;

  const int row0 = blockIdx.y * 64;
  const int col0 = blockIdx.x * 64;
  const int t  = threadIdx.x;
  const int tx = t & 15;
  const int ty = t >> 4;
  const int lrow = t >> 2;
  const int lseg = (t & 3) * 4;

  float acc[4][4] = {};
  for (int k0 = 0; k0 < DD; k0 += BK) {
    const float4 xv = *(const float4*)(Xin + (size_t)(row0 + lrow) * DD + k0 + lseg);
    const float4 wv = *(const float4*)(W   + (size_t)(col0 + lrow) * DD + k0 + lseg);
    Xs[lseg + 0][lrow] = xv.x; Xs[lseg + 1][lrow] = xv.y;
    Xs[lseg + 2][lrow] = xv.z; Xs[lseg + 3][lrow] = xv.w;
    Ws[lseg + 0][lrow] = wv.x; Ws[lseg + 1][lrow] = wv.y;
    Ws[lseg + 2][lrow] = wv.z; Ws[lseg + 3][lrow] = wv.w;
    __syncthreads();
#pragma unroll
    for (int kk = 0; kk < BK; ++kk) {
      float xr[4], wr[4];
#pragma unroll
      for (int a = 0; a < 4; ++a) xr[a] = Xs[kk][ty * 4 + a];
#pragma unroll
      for (int b = 0; b < 4; ++b) wr[b] = Ws[kk][tx * 4 + b];
#pragma unroll
      for (int a = 0; a < 4; ++a)
#pragma unroll
        for (int b = 0; b < 4; ++b) acc[a][b] += xr[a] * wr[b];
    }
    __syncthreads();
  }
#pragma unroll
  for (int a = 0; a < 4; ++a) {
    const int r = row0 + ty * 4 + a;
#pragma unroll
    for (int b2 = 0; b2 < 4; ++b2) {
      const int c = col0 + tx * 4 + b2;
      out[(size_t)r * DD + c] = acc[a][b2] + bias[c];
    }
  }
}

// -------- Kernel B: theta/A batched logits --------
__global__ __launch_bounds__(256) void logits_kernel(
    const float* __restrict__ zx, const float* __restrict__ zy,
    const float* __restrict__ gx, const float* __restrict__ gy,
    float* __restrict__ theta, float* __restrict__ Aout) {
  constexpr int BK = 16;
  __shared__ float Xs[BK][64 + 1];
  __shared__ float Ys[BK][64 + 1];

  const int bz = blockIdx.z;
  const int b = bz >> 1, w = bz & 1;
  const float* X = (w ? gx : zx) + (size_t)b * LL * DD;
  const float* Y = (w ? gy : zy) + (size_t)b * LL * DD;
  float* out = (w ? Aout : theta) + (size_t)b * L2E;

  const int row0 = blockIdx.y * 64;
  const int col0 = blockIdx.x * 64;
  const int t  = threadIdx.x;
  const int tx = t & 15;
  const int ty = t >> 4;
  const int lrow = t >> 2;
  const int lseg = (t & 3) * 4;

  float acc[4][4] = {};
  for (int k0 = 0; k0 < DD; k0 += BK) {
    const float4 xv = *(const float4*)(X + (size_t)(row0 + lrow) * DD + k0 + lseg);
    const float4 yv = *(const float4*)(Y + (size_t)(col0 + lrow) * DD + k0 + lseg);
    Xs[lseg + 0][lrow] = xv.x; Xs[lseg + 1][lrow] = xv.y;
    Xs[lseg + 2][lrow] = xv.z; Xs[lseg + 3][lrow] = xv.w;
    Ys[lseg + 0][lrow] = yv.x; Ys[lseg + 1][lrow] = yv.y;
    Ys[lseg + 2][lrow] = yv.z; Ys[lseg + 3][lrow] = yv.w;
    __syncthreads();
#pragma unroll
    for (int kk = 0; kk < BK; ++kk) {
      float xr[4], yr[4];
#pragma unroll
      for (int a = 0; a < 4; ++a) xr[a] = Xs[kk][ty * 4 + a];
#pragma unroll
      for (int b2 = 0; b2 < 4; ++b2) yr[b2] = Ys[kk][tx * 4 + b2];
#pragma unroll
      for (int a = 0; a < 4; ++a)
#pragma unroll
        for (int b2 = 0; b2 < 4; ++b2) acc[a][b2] += xr[a] * yr[b2];
    }
    __syncthreads();
  }
#pragma unroll
  for (int a = 0; a < 4; ++a) {
    const int r = row0 + ty * 4 + a;
#pragma unroll
    for (int b2 = 0; b2 < 4; ++b2) {
      const int c = col0 + tx * 4 + b2;
      const float v = acc[a][b2];
      out[(size_t)r * LL + c] = w ? logsigmoid_f(v) : softplus_f(v);
    }
  }
}

// -------- row-major theta,A -> packed bf16x2 compact-aligned diag --------
__global__ __launch_bounds__(256) void row2diag(
    const float* __restrict__ theta, const float* __restrict__ A,
    unsigned* __restrict__ TAc) {
  __shared__ float tT[64 * 66];
  __shared__ float tA[64 * 66];
  const int b = blockIdx.z;
  const float* inT = theta + (size_t)b * L2E;
  const float* inA = A + (size_t)b * L2E;
  unsigned* out = TAc + (size_t)b * LDIAG;
  const int r0 = blockIdx.y * 64, c0 = blockIdx.x * 64;
  const int t = threadIdx.x, lane = t & 63, grp = t >> 6;
  for (int it = 0; it < 16; ++it) {
    const int rr = it * 4 + grp;
    tT[rr * 66 + lane] = inT[(size_t)(r0 + rr) * LL + c0 + lane];
    tA[rr * 66 + lane] = inA[(size_t)(r0 + rr) * LL + c0 + lane];
  }
  __syncthreads();
  for (int si = grp; si < 127; si += 4) {
    const int s = r0 + c0 + si;
    const int rlo = max(r0, s - c0 - 63);
    const int rhi = min(r0 + 63, s - c0);
    const int base = Dmap(s) - lofs(s);
    const int r = rlo + lane;
    if (r <= rhi) {
      const int ii = (r - r0) * 66 + (s - r - c0);
      const unsigned ut = __bfloat16_as_ushort(__float2bfloat16(tT[ii]));
      const unsigned ua = __bfloat16_as_ushort(__float2bfloat16(tA[ii]));
      out[base + r] = (ua << 16) | ut;
    }
  }
}

// -------- compact-aligned bf16 E -> row-major fp32 (aln) --------
__global__ __launch_bounds__(256) void diag2row(
    const unsigned short* __restrict__ Edc, float* __restrict__ aln) {
  __shared__ float tile[64 * 66];
  const int b = blockIdx.z;
  const int r0 = blockIdx.y * 64;
  const int c0 = blockIdx.x * 64;
  const unsigned short* E = Edc + (size_t)b * LDIAG;
  float* out = aln + (size_t)b * L2E;
  const int t = threadIdx.x;
  const int lane = t & 63;
  const int grp = t >> 6;
  for (int si = grp; si < 127; si += 4) {
    const int s = r0 + c0 + si;
    const int rlo = max(r0, s - c0 - 63);
    const int rhi = min(r0 + 63, s - c0);
    const int base = Dmap(s) - lofs(s);
    const int r = rlo + lane;
    if (r <= rhi) {
      tile[(r - r0) * 66 + (s - r - c0)] =
          __uint_as_float(((unsigned)E[base + r]) << 16);
    }
  }
  __syncthreads();
  for (int it = 0; it < 16; ++it) {
    const int rr = it * 4 + grp;
    out[(size_t)(r0 + rr) * LL + c0 + lane] = tile[rr * 66 + lane];
  }
}

// publish flag: LDS-only release (ring data is LDS; avoid vmcnt(0) drain)
__device__ __forceinline__ void lds_release_store(int* p, int v) {
  asm volatile("s_waitcnt lgkmcnt(0)" ::: "memory");
  __hip_atomic_store(p, v, __ATOMIC_RELAXED, __HIP_MEMORY_SCOPE_WORKGROUP);
}

// -------- NW forward: vectorized streams (uint4 TA load, float4 V store) ----
__global__ __launch_bounds__(192, 1) void nw_fwd(
    const unsigned* __restrict__ TAc, float* __restrict__ Vr) {
  __shared__ int Pf[4];
  __shared__ float BvF[2][1024];

  const int b = blockIdx.x;
  const unsigned* TA = TAc + (size_t)b * LDIAG;
  float* V = Vr + (size_t)b * (1536 * LL);

  const int t = threadIdx.x;
  const int w = t >> 6, l = t & 63;
  const int rowb = 4 * t;
  const int kb = 256 * w + 2;

  if (t < 4) Pf[t] = 0;
  __syncthreads();

  uint4 pq4[4];
#pragma unroll
  for (int du = 0; du < 4; ++du) {
    const int s0 = kb - 2 + du;
    pq4[(2 + du) & 3] = *(const uint4*)(TA + (Dmap(s0) + rowb - lofs(s0)));
  }
  int sL = kb + 2;
  int iL = Dmap(sL) + rowb - lofs(sL);
  int iS4 = (kb - 2) * LL + rowb;
  float p1[4], p2[4];
#pragma unroll
  for (int r = 0; r < 4; ++r) { p1[r] = NEGF; p2[r] = NEGF; }
  float rvh = NEGF;
  float pv3 = NEGF;

  for (int kg = kb; kg < kb + 1024; kg += 8) {
    if (l == 0 && w > 0 && kg < kb + 768) {
      const int need = min(kg + 6, kb + 766);
      while (__hip_atomic_load(&Pf[w - 1], __ATOMIC_ACQUIRE,
                               __HIP_MEMORY_SCOPE_WORKGROUP) < need) {}
    }
#pragma unroll
    for (int u = 0; u < 8; ++u) {
      const int k = kg + u;
      const int su = (2 + u) & 3;  // k & 3 (kb ≡ 2 mod 8)
      float rv = __shfl_up(pv3, 1);
      if (l == 0) {
        if (w == 0) rv = NEGF;
        else rv = BvF[w - 1][min(k - kb + 255, 1023)];
      }
      float rdg = rvh;
      if (l == 0 && w == 0) rdg = (k == 2) ? 0.f : NEGF;
      const int d = k - rowb - 2;
      const uint4 q = pq4[su];
      const unsigned qc[4] = {q.x, q.y, q.z, q.w};
      float vv[4];
#pragma unroll
      for (int r = 0; r < 4; ++r) {
        const float Vl = p1[r];
        const float Vu = (r == 0) ? rv : p1[r - 1];
        const float Vg = (r == 0) ? rdg : p2[r - 1];
        const float av = bf_hi(qc[r]), tv = bf_lo(qc[r]);
        const float lft = av + Vl, up = av + Vu;
        const float mx = fmaxf(Vg, fmaxf(lft, up));
        const float val = tv + mx +
            __logf(__expf(Vg - mx) + __expf(lft - mx) + __expf(up - mx));
        vv[r] = ((unsigned)(d - r) <= 767u) ? val : NEGF;
      }
      pq4[su] = *(const uint4*)(TA + iL);  // for step k+4 (s = k+2)
      iL += dIa(sL); ++sL;
      *(float4*)(V + iS4) = make_float4(vv[0], vv[1], vv[2], vv[3]);
      iS4 += LL;
      if (l == 63 && w < 2) BvF[w][k - kb] = vv[3];
      pv3 = vv[3];
      rvh = rv;
#pragma unroll
      for (int r = 0; r < 4; ++r) { p2[r] = p1[r]; p1[r] = vv[r]; }
    }
    if (l == 63 && w < 2) lds_release_store(&Pf[w], kg + 7);
  }
}

// -------- NW backward: vectorized streams, ushort4 E store --------
__global__ __launch_bounds__(192, 1) void nw_bwd(
    const unsigned* __restrict__ TAc, const float* __restrict__ Vr,
    unsigned short* __restrict__ Edc) {
  __shared__ int Pb[4];
  __shared__ float Bv2[2][1024];
  __shared__ float Be2[2][1024];

  const int b = blockIdx.x;
  const unsigned* TA = TAc + (size_t)b * LDIAG;
  const float* V = Vr + (size_t)b * (1536 * LL);
  unsigned short* Eo = Edc + (size_t)b * LDIAG;

  const int t = threadIdx.x;
  const int w = t >> 6, l = t & 63;
  const int rowb = 4 * t;
  const int kb = 256 * w + 2;
  const int ke = kb + 1023;

  if (t < 4) Pb[t] = 0x7fffffff;
  __syncthreads();

  float4 sVv4[4];       // V at s=k-2, rows rowb..rowb+3
  uint4 sK1q[4];        // packed (th,a) at s=k-1, rows rowb..rowb+3
  unsigned sK15b[4];    // boundary lanes' 5th element (row rowb+4)
#pragma unroll
  for (int du = 0; du < 4; ++du) {
    const int slot = (1 - du) & 3;
    const int sv = ke - 2 - du;
    sVv4[slot] = *(const float4*)(V + (sv * LL + rowb));
    const int sk = ke - 1 - du;
    const int ik = Dmap(sk) + rowb - lofs(sk);
    sK1q[slot] = *(const uint4*)(TA + ik);
    sK15b[slot] = TA[ik + 4];
  }
  int iV = (ke - 6) * LL + rowb;
  int sK1s = ke - 5;
  int iK1 = Dmap(sK1s) + rowb - lofs(sK1s);
  // sKt pipeline: th at s=k, rows rowb+1..rowb+4; prologue from s=ke
  float sKtb[2][4];
  {
    const int j0 = Dmap(ke) + rowb - lofs(ke);
#pragma unroll
    for (int r = 0; r < 4; ++r) sKtb[0][r] = bf_lo(TA[j0 + 1 + r]);
  }
  int sE = ke - 2;
  int iE = Dmap(sE) + rowb - lofs(sE);
  float N1v[4], N1e[4], N2v[4], N2e[4], hV[4], hE[4];
#pragma unroll
  for (int r = 0; r < 4; ++r) {
    N1v[r] = 0.f; N1e[r] = 0.f; N2v[r] = 0.f; N2e[r] = 0.f; hV[r] = 0.f; hE[r] = 0.f;
  }
  float pv0 = 0.f, pe0 = 0.f;

  for (int kg = ke; kg > ke - 1024; kg -= 8) {
    if (l == 63 && w < 2 && kg >= kb + 255) {
      const int need = max(kg - 6, kb + 256);
      while (__hip_atomic_load(&Pb[w + 1], __ATOMIC_ACQUIRE,
                               __HIP_MEMORY_SCOPE_WORKGROUP) > need) {}
    }
#pragma unroll
    for (int u = 0; u < 8; ++u) {
      const int k = kg - u;
      const int su = (1 - u) & 3;   // k & 3 (ke ≡ 1 mod 8)
      const int cb = u & 1, nb = (u + 1) & 1;
      N1v[3] = __shfl_down(pv0, 1);
      N1e[3] = __shfl_down(pe0, 1);
      if (l == 63) {
        if (w < 2) {
          const int bi = min(ke - k + 255, 1023);
          N1v[3] = Bv2[w][bi];
          N1e[3] = Be2[w][bi];
        } else {
          N1v[3] = 0.f; N1e[3] = 0.f;
        }
      }
      const int d = k - rowb - 2;
      const uint4 q1 = sK1q[su];
      unsigned fifth = __shfl_down(q1.x, 1);
      if (l == 63) fifth = sK15b[su];
      const unsigned s1c[5] = {q1.x, q1.y, q1.z, q1.w, fifth};
      const float4 vq = sVv4[su];
      const float vcmp[4] = {vq.x, vq.y, vq.z, vq.w};
      float e[4], vc[4];
#pragma unroll
      for (int r = 0; r < 4; ++r) {
        vc[r] = vcmp[r];
        const bool ok  = (unsigned)(d - r) <= 767u;
        const bool jlt = (d - r) < 767;
        const bool ilt = (rowb + r) < 767;
        float acc = 0.f;
        if (ilt && jlt) acc += N2e[r] * __expf(vc[r] - N2v[r] + sKtb[cb][r]);
        if (jlt) acc += hE[r] * __expf(bf_hi(s1c[r]) + vc[r] - hV[r] + bf_lo(s1c[r]));
        if (ilt) acc += N1e[r] * __expf(bf_hi(s1c[r + 1]) + vc[r] - N1v[r] + bf_lo(s1c[r + 1]));
        e[r] = ok ? acc : 0.f;
      }
      if (k == 2 * LL && t == 191) e[3] = 1.f;
      // capture th(s=k-1, rows rowb+1..rowb+4) for step k-1 — BEFORE refill
#pragma unroll
      for (int r = 0; r < 4; ++r) sKtb[nb][r] = bf_lo(s1c[r + 1]);
      // refills for step k-4
      sVv4[su] = *(const float4*)(V + max(iV, 0));
      iV -= LL;
      {
        const int ic = max(iK1, 0);
        sK1q[su] = *(const uint4*)(TA + ic);
        if (l == 63) sK15b[su] = TA[ic + 4];
        iK1 -= dIa(sK1s - 1); --sK1s;
      }
      // E store (s = k-2): one ushort4 if any row valid (gaps >=3 absorb overhang)
      if ((unsigned)d <= 770u) {
        ushort4 st;
        st.x = __bfloat16_as_ushort(__float2bfloat16(e[0]));
        st.y = __bfloat16_as_ushort(__float2bfloat16(e[1]));
        st.z = __bfloat16_as_ushort(__float2bfloat16(e[2]));
        st.w = __bfloat16_as_ushort(__float2bfloat16(e[3]));
        *(ushort4*)(Eo + iE) = st;
      }
      iE -= dIa(sE - 1); --sE;
      // boundary publish: own row 0 values for wave w-1
      if (l == 0 && w > 0) {
        Bv2[w - 1][ke - k] = vc[0];
        Be2[w - 1][ke - k] = e[0];
      }
      pv0 = vc[0];
      pe0 = e[0];
#pragma unroll
      for (int r = 0; r < 4; ++r) { N2v[r] = N1v[r]; N2e[r] = N1e[r]; }
      N1v[0] = vc[1]; N1e[0] = e[1];
      N1v[1] = vc[2]; N1e[1] = e[2];
      N1v[2] = vc[3]; N1e[2] = e[3];
#pragma unroll
      for (int r = 0; r < 4; ++r) { hV[r] = vc[r]; hE[r] = e[r]; }
    }
    if (l == 0 && w > 0) lds_release_store(&Pb[w], kg - 7);
  }
}

}  // namespace

extern "C" void kernel_launch(void* const* d_in, const int* in_sizes, int n_in,
                              void* d_out, int out_size, void* d_ws, size_t ws_size,
                              hipStream_t stream) {
  const float* hx = (const float*)d_in[0];
  const float* hy = (const float*)d_in[1];
  const float* Wm = (const float*)d_in[2];
  const float* bm = (const float*)d_in[3];
  const float* Wg = (const float*)d_in[4];
  const float* bg = (const float*)d_in[5];

  float* aln   = (float*)d_out;
  float* theta = aln + (size_t)BB * L2E;
  float* A     = theta + (size_t)BB * L2E;

  // phase-2 workspace: TAc (bf16x2 compact-aligned, 19.1MB) + Vr (rect fp32,
  // 37.7MB) + Edc (bf16 compact-aligned, 9.6MB) = 66.4MB
  unsigned* TAc = (unsigned*)d_ws;
  float* Vr = (float*)d_ws + (size_t)BB * LDIAG;
  unsigned short* Edc = (unsigned short*)(Vr + (size_t)BB * (1536 * LL));
  // phase-1 workspace aliases the same region (dead after logits)
  float* zx = (float*)d_ws;
  float* zy = zx + (size_t)BB * LL * DD;
  float* gx = zy + (size_t)BB * LL * DD;
  float* gy = gx + (size_t)BB * LL * DD;

  linear_kernel<<<dim3(DD / 64, (BB * LL) / 64, 4), 256, 0, stream>>>(
      hx, hy, Wm, bm, Wg, bg, zx, zy, gx, gy);
  logits_kernel<<<dim3(LL / 64, LL / 64, BB * 2), 256, 0, stream>>>(
      zx, zy, gx, gy, theta, A);
  row2diag<<<dim3(LL / 64, LL / 64, BB), 256, 0, stream>>>(theta, A, TAc);

  nw_fwd<<<dim3(BB), 192, 0, stream>>>(TAc, Vr);
  nw_bwd<<<dim3(BB), 192, 0, stream>>>(TAc, Vr, Edc);

  diag2row<<<dim3(LL / 64, LL / 64, BB), 256, 0, stream>>>(Edc, aln);
}

// Round 12
// 1822.843 us; speedup vs baseline: 1.3214x; 1.1052x over previous
//
#include <hip/hip_runtime.h>
#include <hip/hip_bf16.h>
#include <math.h>

namespace {

constexpr int BB = 8;
constexpr int LL = 768;
constexpr int DD = 512;
constexpr int L2E = LL * LL;
constexpr int LDIAG = L2E + 8192;
constexpr float NEGF = -1e9f;

typedef __attribute__((ext_vector_type(8))) short bf16x8;
typedef __attribute__((ext_vector_type(8))) unsigned short u16x8;
typedef __attribute__((ext_vector_type(4))) float f32x4;

__device__ __forceinline__ float softplus_f(float x) {
  return x > 0.f ? x + log1pf(expf(-x)) : log1pf(expf(x));
}
__device__ __forceinline__ float logsigmoid_f(float x) {
  return x > 0.f ? -log1pf(expf(-x)) : x - log1pf(expf(x));
}

__device__ __forceinline__ float bf_lo(unsigned u) { return __uint_as_float(u << 16); }
__device__ __forceinline__ float bf_hi(unsigned u) { return __uint_as_float(u & 0xffff0000u); }

__device__ __forceinline__ int lofs(int s) { return (s > LL - 1) ? (s - (LL - 1)) : 0; }

__device__ __forceinline__ int Dmap(int s) {
  if (s <= LL - 1) {
    const int m = s >> 2, i = s & 3;
    const int c = (i == 0) ? 4 : (i == 1) ? 8 : (i == 2) ? 16 : 24;
    return 8 * m * m + (20 + 4 * i) * m + c;
  }
  const int q = (s - LL) >> 2, i = (s - LL) & 3;
  const int base = 298757 + 3092 * q - 8 * q * q;
  const int off = (i == 0) ? 0 : (i == 1) ? (773 - 4 * q)
                : (i == 2) ? (1546 - 8 * q) : (2315 - 12 * q);
  return base + off;
}
__device__ __forceinline__ int dDa(int s) {
  if (s < LL - 1) return s + 4 + ((-s) & 3);
  if (s == LL - 1) return 773;
  return 1539 - s + ((s + 2) & 3);
}
__device__ __forceinline__ int dIa(int s) { return dDa(s) - ((s >= LL - 1) ? 1 : 0); }

// -------- fp32 -> bf16 convert --------
__global__ __launch_bounds__(256) void tobf16(
    const float* __restrict__ src, unsigned short* __restrict__ dst, int n) {
  const int i = (blockIdx.x * 256 + threadIdx.x) * 4;
  if (i < n) {
    const float4 v = *(const float4*)(src + i);
    ushort4 o;
    o.x = __bfloat16_as_ushort(__float2bfloat16(v.x));
    o.y = __bfloat16_as_ushort(__float2bfloat16(v.y));
    o.z = __bfloat16_as_ushort(__float2bfloat16(v.z));
    o.w = __bfloat16_as_ushort(__float2bfloat16(v.w));
    *(ushort4*)(dst + i) = o;
  }
}

// -------- MFMA GEMM 1: Zb[which] = Xb[which&1] @ Wb[which>>1]^T + bias ------
// X: (6144,512) bf16 row-major; W: (512,512) bf16 row-major; out bf16.
__global__ __launch_bounds__(256) void mfma_linear(
    const unsigned short* __restrict__ Xb, const unsigned short* __restrict__ Wb,
    const float* __restrict__ bm, const float* __restrict__ bg,
    unsigned short* __restrict__ Zb) {
  __shared__ unsigned short As[128][32];
  __shared__ unsigned short Bs[128][32];
  const int which = blockIdx.z;
  const unsigned short* X = Xb + (size_t)(which & 1) * (6144 * 512);
  const unsigned short* W = Wb + (size_t)(which >> 1) * (512 * 512);
  const float* bias = (which >= 2) ? bg : bm;
  unsigned short* out = Zb + (size_t)which * (6144 * 512);
  const int row0 = blockIdx.y * 128, col0 = blockIdx.x * 128;
  const int t = threadIdx.x, wv = t >> 6, l = t & 63;
  const int wm = (wv >> 1) * 64, wn = (wv & 1) * 64;

  f32x4 acc[4][4] = {};
  for (int k0 = 0; k0 < 512; k0 += 32) {
#pragma unroll
    for (int c = t; c < 512; c += 256) {
      const int rowi = c >> 2, seg = (c & 3) << 3;
      *(u16x8*)&As[rowi][seg] = *(const u16x8*)&X[(size_t)(row0 + rowi) * 512 + k0 + seg];
      *(u16x8*)&Bs[rowi][seg] = *(const u16x8*)&W[(size_t)(col0 + rowi) * 512 + k0 + seg];
    }
    __syncthreads();
    bf16x8 af[4], bfr[4];
#pragma unroll
    for (int f = 0; f < 4; ++f) {
      af[f]  = *(const bf16x8*)&As[wm + f * 16 + (l & 15)][(l >> 4) << 3];
      bfr[f] = *(const bf16x8*)&Bs[wn + f * 16 + (l & 15)][(l >> 4) << 3];
    }
#pragma unroll
    for (int fm = 0; fm < 4; ++fm)
#pragma unroll
      for (int fn = 0; fn < 4; ++fn)
        acc[fm][fn] = __builtin_amdgcn_mfma_f32_16x16x32_bf16(
            af[fm], bfr[fn], acc[fm][fn], 0, 0, 0);
    __syncthreads();
  }
#pragma unroll
  for (int fm = 0; fm < 4; ++fm) {
    const int rbase = row0 + wm + fm * 16 + ((l >> 4) << 2);
#pragma unroll
    for (int fn = 0; fn < 4; ++fn) {
      const int col = col0 + wn + fn * 16 + (l & 15);
      const float bv = bias[col];
      const f32x4 v = acc[fm][fn];
#pragma unroll
      for (int j = 0; j < 4; ++j)
        out[(size_t)(rbase + j) * 512 + col] =
            __bfloat16_as_ushort(__float2bfloat16(v[j] + bv));
    }
  }
}

// -------- MFMA GEMM 2: theta/A = act(Zx @ Zy^T) per (b, w) -----------------
__global__ __launch_bounds__(256) void mfma_logits(
    const unsigned short* __restrict__ Zb,
    float* __restrict__ theta, float* __restrict__ Aout) {
  __shared__ unsigned short As[128][32];
  __shared__ unsigned short Bs[128][32];
  const int bz = blockIdx.z;
  const int b = bz >> 1, w = bz & 1;
  const unsigned short* X = Zb + (size_t)(w ? 2 : 0) * (6144 * 512) + (size_t)b * (768 * 512);
  const unsigned short* Y = Zb + (size_t)(w ? 3 : 1) * (6144 * 512) + (size_t)b * (768 * 512);
  float* out = (w ? Aout : theta) + (size_t)b * L2E;
  const int row0 = blockIdx.y * 128, col0 = blockIdx.x * 128;
  const int t = threadIdx.x, wv = t >> 6, l = t & 63;
  const int wm = (wv >> 1) * 64, wn = (wv & 1) * 64;

  f32x4 acc[4][4] = {};
  for (int k0 = 0; k0 < 512; k0 += 32) {
#pragma unroll
    for (int c = t; c < 512; c += 256) {
      const int rowi = c >> 2, seg = (c & 3) << 3;
      *(u16x8*)&As[rowi][seg] = *(const u16x8*)&X[(size_t)(row0 + rowi) * 512 + k0 + seg];
      *(u16x8*)&Bs[rowi][seg] = *(const u16x8*)&Y[(size_t)(col0 + rowi) * 512 + k0 + seg];
    }
    __syncthreads();
    bf16x8 af[4], bfr[4];
#pragma unroll
    for (int f = 0; f < 4; ++f) {
      af[f]  = *(const bf16x8*)&As[wm + f * 16 + (l & 15)][(l >> 4) << 3];
      bfr[f] = *(const bf16x8*)&Bs[wn + f * 16 + (l & 15)][(l >> 4) << 3];
    }
#pragma unroll
    for (int fm = 0; fm < 4; ++fm)
#pragma unroll
      for (int fn = 0; fn < 4; ++fn)
        acc[fm][fn] = __builtin_amdgcn_mfma_f32_16x16x32_bf16(
            af[fm], bfr[fn], acc[fm][fn], 0, 0, 0);
    __syncthreads();
  }
#pragma unroll
  for (int fm = 0; fm < 4; ++fm) {
    const int rbase = row0 + wm + fm * 16 + ((l >> 4) << 2);
#pragma unroll
    for (int fn = 0; fn < 4; ++fn) {
      const int col = col0 + wn + fn * 16 + (l & 15);
      const f32x4 v = acc[fm][fn];
#pragma unroll
      for (int j = 0; j < 4; ++j)
        out[(size_t)(rbase + j) * LL + col] = w ? logsigmoid_f(v[j]) : softplus_f(v[j]);
    }
  }
}

// -------- row-major theta,A -> packed bf16x2 compact-aligned diag --------
__global__ __launch_bounds__(256) void row2diag(
    const float* __restrict__ theta, const float* __restrict__ A,
    unsigned* __restrict__ TAc) {
  __shared__ float tT[64 * 66];
  __shared__ float tA[64 * 66];
  const int b = blockIdx.z;
  const float* inT = theta + (size_t)b * L2E;
  const float* inA = A + (size_t)b * L2E;
  unsigned* out = TAc + (size_t)b * LDIAG;
  const int r0 = blockIdx.y * 64, c0 = blockIdx.x * 64;
  const int t = threadIdx.x, lane = t & 63, grp = t >> 6;
  for (int it = 0; it < 16; ++it) {
    const int rr = it * 4 + grp;
    tT[rr * 66 + lane] = inT[(size_t)(r0 + rr) * LL + c0 + lane];
    tA[rr * 66 + lane] = inA[(size_t)(r0 + rr) * LL + c0 + lane];
  }
  __syncthreads();
  for (int si = grp; si < 127; si += 4) {
    const int s = r0 + c0 + si;
    const int rlo = max(r0, s - c0 - 63);
    const int rhi = min(r0 + 63, s - c0);
    const int base = Dmap(s) - lofs(s);
    const int r = rlo + lane;
    if (r <= rhi) {
      const int ii = (r - r0) * 66 + (s - r - c0);
      const unsigned ut = __bfloat16_as_ushort(__float2bfloat16(tT[ii]));
      const unsigned ua = __bfloat16_as_ushort(__float2bfloat16(tA[ii]));
      out[base + r] = (ua << 16) | ut;
    }
  }
}

// -------- compact-aligned bf16 E -> row-major fp32 (aln) --------
__global__ __launch_bounds__(256) void diag2row(
    const unsigned short* __restrict__ Edc, float* __restrict__ aln) {
  __shared__ float tile[64 * 66];
  const int b = blockIdx.z;
  const int r0 = blockIdx.y * 64;
  const int c0 = blockIdx.x * 64;
  const unsigned short* E = Edc + (size_t)b * LDIAG;
  float* out = aln + (size_t)b * L2E;
  const int t = threadIdx.x;
  const int lane = t & 63;
  const int grp = t >> 6;
  for (int si = grp; si < 127; si += 4) {
    const int s = r0 + c0 + si;
    const int rlo = max(r0, s - c0 - 63);
    const int rhi = min(r0 + 63, s - c0);
    const int base = Dmap(s) - lofs(s);
    const int r = rlo + lane;
    if (r <= rhi) {
      tile[(r - r0) * 66 + (s - r - c0)] =
          __uint_as_float(((unsigned)E[base + r]) << 16);
    }
  }
  __syncthreads();
  for (int it = 0; it < 16; ++it) {
    const int rr = it * 4 + grp;
    out[(size_t)(r0 + rr) * LL + c0 + lane] = tile[rr * 66 + lane];
  }
}

__device__ __forceinline__ void lds_release_store(int* p, int v) {
  asm volatile("s_waitcnt lgkmcnt(0)" ::: "memory");
  __hip_atomic_store(p, v, __ATOMIC_RELAXED, __HIP_MEMORY_SCOPE_WORKGROUP);
}

// -------- NW forward: depth-8 prefetch, vectorized streams --------
__global__ __launch_bounds__(192, 1) void nw_fwd(
    const unsigned* __restrict__ TAc, float* __restrict__ Vr) {
  __shared__ int Pf[4];
  __shared__ float BvF[2][1024];

  const int b = blockIdx.x;
  const unsigned* TA = TAc + (size_t)b * LDIAG;
  float* V = Vr + (size_t)b * (1536 * LL);

  const int t = threadIdx.x;
  const int w = t >> 6, l = t & 63;
  const int rowb = 4 * t;
  const int kb = 256 * w + 2;

  if (t < 4) Pf[t] = 0;
  __syncthreads();

  uint4 pq4[8];
#pragma unroll
  for (int du = 0; du < 8; ++du) {
    const int s0 = kb - 2 + du;
    pq4[(2 + du) & 7] = *(const uint4*)(TA + (Dmap(s0) + rowb - lofs(s0)));
  }
  int sL = kb + 6;
  int iL = Dmap(sL) + rowb - lofs(sL);
  int iS4 = (kb - 2) * LL + rowb;
  float p1[4], p2[4];
#pragma unroll
  for (int r = 0; r < 4; ++r) { p1[r] = NEGF; p2[r] = NEGF; }
  float rvh = NEGF;
  float pv3 = NEGF;

  for (int kg = kb; kg < kb + 1024; kg += 8) {
    if (l == 0 && w > 0 && kg < kb + 768) {
      const int need = min(kg + 6, kb + 766);
      while (__hip_atomic_load(&Pf[w - 1], __ATOMIC_ACQUIRE,
                               __HIP_MEMORY_SCOPE_WORKGROUP) < need) {}
    }
#pragma unroll
    for (int u = 0; u < 8; ++u) {
      const int k = kg + u;
      const int su = (2 + u) & 7;  // k & 7 (kb ≡ 2 mod 8)
      float rv = __shfl_up(pv3, 1);
      if (l == 0) {
        if (w == 0) rv = NEGF;
        else rv = BvF[w - 1][min(k - kb + 255, 1023)];
      }
      float rdg = rvh;
      if (l == 0 && w == 0) rdg = (k == 2) ? 0.f : NEGF;
      const int d = k - rowb - 2;
      const uint4 q = pq4[su];
      const unsigned qc[4] = {q.x, q.y, q.z, q.w};
      float vv[4];
#pragma unroll
      for (int r = 0; r < 4; ++r) {
        const float Vl = p1[r];
        const float Vu = (r == 0) ? rv : p1[r - 1];
        const float Vg = (r == 0) ? rdg : p2[r - 1];
        const float av = bf_hi(qc[r]), tv = bf_lo(qc[r]);
        const float lft = av + Vl, up = av + Vu;
        const float mx = fmaxf(Vg, fmaxf(lft, up));
        const float val = tv + mx +
            __logf(__expf(Vg - mx) + __expf(lft - mx) + __expf(up - mx));
        vv[r] = ((unsigned)(d - r) <= 767u) ? val : NEGF;
      }
      pq4[su] = *(const uint4*)(TA + iL);  // for step k+8 (s = k+6)
      iL += dIa(sL); ++sL;
      *(float4*)(V + iS4) = make_float4(vv[0], vv[1], vv[2], vv[3]);
      iS4 += LL;
      if (l == 63 && w < 2) BvF[w][k - kb] = vv[3];
      pv3 = vv[3];
      rvh = rv;
#pragma unroll
      for (int r = 0; r < 4; ++r) { p2[r] = p1[r]; p1[r] = vv[r]; }
    }
    if (l == 63 && w < 2) lds_release_store(&Pf[w], kg + 7);
  }
}

// -------- NW backward: depth-8 prefetch, vectorized streams --------
__global__ __launch_bounds__(192, 1) void nw_bwd(
    const unsigned* __restrict__ TAc, const float* __restrict__ Vr,
    unsigned short* __restrict__ Edc) {
  __shared__ int Pb[4];
  __shared__ float Bv2[2][1024];
  __shared__ float Be2[2][1024];

  const int b = blockIdx.x;
  const unsigned* TA = TAc + (size_t)b * LDIAG;
  const float* V = Vr + (size_t)b * (1536 * LL);
  unsigned short* Eo = Edc + (size_t)b * LDIAG;

  const int t = threadIdx.x;
  const int w = t >> 6, l = t & 63;
  const int rowb = 4 * t;
  const int kb = 256 * w + 2;
  const int ke = kb + 1023;

  if (t < 4) Pb[t] = 0x7fffffff;
  __syncthreads();

  float4 sVv4[8];
  uint4 sK1q[8];
  unsigned sK15b[8];
#pragma unroll
  for (int du = 0; du < 8; ++du) {
    const int slot = (1 - du) & 7;
    const int sv = ke - 2 - du;
    sVv4[slot] = *(const float4*)(V + (sv * LL + rowb));
    const int sk = ke - 1 - du;
    const int ik = Dmap(sk) + rowb - lofs(sk);
    sK1q[slot] = *(const uint4*)(TA + ik);
    sK15b[slot] = TA[ik + 4];
  }
  int iV = (ke - 10) * LL + rowb;
  int sK1s = ke - 9;
  int iK1 = Dmap(sK1s) + rowb - lofs(sK1s);
  float sKtb[2][4];
  {
    const int j0 = Dmap(ke) + rowb - lofs(ke);
#pragma unroll
    for (int r = 0; r < 4; ++r) sKtb[0][r] = bf_lo(TA[j0 + 1 + r]);
  }
  int sE = ke - 2;
  int iE = Dmap(sE) + rowb - lofs(sE);
  float N1v[4], N1e[4], N2v[4], N2e[4], hV[4], hE[4];
#pragma unroll
  for (int r = 0; r < 4; ++r) {
    N1v[r] = 0.f; N1e[r] = 0.f; N2v[r] = 0.f; N2e[r] = 0.f; hV[r] = 0.f; hE[r] = 0.f;
  }
  float pv0 = 0.f, pe0 = 0.f;

  for (int kg = ke; kg > ke - 1024; kg -= 8) {
    if (l == 63 && w < 2 && kg >= kb + 255) {
      const int need = max(kg - 6, kb + 256);
      while (__hip_atomic_load(&Pb[w + 1], __ATOMIC_ACQUIRE,
                               __HIP_MEMORY_SCOPE_WORKGROUP) > need) {}
    }
#pragma unroll
    for (int u = 0; u < 8; ++u) {
      const int k = kg - u;
      const int su = (1 - u) & 7;   // k & 7 (ke ≡ 1 mod 8)
      const int cb = u & 1, nb = (u + 1) & 1;
      N1v[3] = __shfl_down(pv0, 1);
      N1e[3] = __shfl_down(pe0, 1);
      if (l == 63) {
        if (w < 2) {
          const int bi = min(ke - k + 255, 1023);
          N1v[3] = Bv2[w][bi];
          N1e[3] = Be2[w][bi];
        } else {
          N1v[3] = 0.f; N1e[3] = 0.f;
        }
      }
      const int d = k - rowb - 2;
      const uint4 q1 = sK1q[su];
      unsigned fifth = __shfl_down(q1.x, 1);
      if (l == 63) fifth = sK15b[su];
      const unsigned s1c[5] = {q1.x, q1.y, q1.z, q1.w, fifth};
      const float4 vq = sVv4[su];
      const float vcmp[4] = {vq.x, vq.y, vq.z, vq.w};
      float e[4], vc[4];
#pragma unroll
      for (int r = 0; r < 4; ++r) {
        vc[r] = vcmp[r];
        const bool ok  = (unsigned)(d - r) <= 767u;
        const bool jlt = (d - r) < 767;
        const bool ilt = (rowb + r) < 767;
        float acc = 0.f;
        if (ilt && jlt) acc += N2e[r] * __expf(vc[r] - N2v[r] + sKtb[cb][r]);
        if (jlt) acc += hE[r] * __expf(bf_hi(s1c[r]) + vc[r] - hV[r] + bf_lo(s1c[r]));
        if (ilt) acc += N1e[r] * __expf(bf_hi(s1c[r + 1]) + vc[r] - N1v[r] + bf_lo(s1c[r + 1]));
        e[r] = ok ? acc : 0.f;
      }
      if (k == 2 * LL && t == 191) e[3] = 1.f;
#pragma unroll
      for (int r = 0; r < 4; ++r) sKtb[nb][r] = bf_lo(s1c[r + 1]);
      // refills for step k-8
      sVv4[su] = *(const float4*)(V + max(iV, 0));
      iV -= LL;
      {
        const int ic = max(iK1, 0);
        sK1q[su] = *(const uint4*)(TA + ic);
        if (l == 63) sK15b[su] = TA[ic + 4];
        iK1 -= dIa(sK1s - 1); --sK1s;
      }
      if ((unsigned)d <= 770u) {
        ushort4 st;
        st.x = __bfloat16_as_ushort(__float2bfloat16(e[0]));
        st.y = __bfloat16_as_ushort(__float2bfloat16(e[1]));
        st.z = __bfloat16_as_ushort(__float2bfloat16(e[2]));
        st.w = __bfloat16_as_ushort(__float2bfloat16(e[3]));
        *(ushort4*)(Eo + iE) = st;
      }
      iE -= dIa(sE - 1); --sE;
      if (l == 0 && w > 0) {
        Bv2[w - 1][ke - k] = vc[0];
        Be2[w - 1][ke - k] = e[0];
      }
      pv0 = vc[0];
      pe0 = e[0];
#pragma unroll
      for (int r = 0; r < 4; ++r) { N2v[r] = N1v[r]; N2e[r] = N1e[r]; }
      N1v[0] = vc[1]; N1e[0] = e[1];
      N1v[1] = vc[2]; N1e[1] = e[2];
      N1v[2] = vc[3]; N1e[2] = e[3];
#pragma unroll
      for (int r = 0; r < 4; ++r) { hV[r] = vc[r]; hE[r] = e[r]; }
    }
    if (l == 0 && w > 0) lds_release_store(&Pb[w], kg - 7);
  }
}

}  // namespace

extern "C" void kernel_launch(void* const* d_in, const int* in_sizes, int n_in,
                              void* d_out, int out_size, void* d_ws, size_t ws_size,
                              hipStream_t stream) {
  const float* hx = (const float*)d_in[0];
  const float* hy = (const float*)d_in[1];
  const float* Wm = (const float*)d_in[2];
  const float* bm = (const float*)d_in[3];
  const float* Wg = (const float*)d_in[4];
  const float* bg = (const float*)d_in[5];

  float* aln   = (float*)d_out;
  float* theta = aln + (size_t)BB * L2E;
  float* A     = theta + (size_t)BB * L2E;

  // phase-1 (GEMM) workspace: bf16 inputs + bf16 Z outputs (38.8MB)
  unsigned short* hxb = (unsigned short*)d_ws;
  unsigned short* hyb = hxb + (size_t)6144 * 512;
  unsigned short* Wmb = hyb + (size_t)6144 * 512;   // Xb base = hxb
  unsigned short* Wgb = Wmb + (size_t)512 * 512;
  unsigned short* Zb  = Wgb + (size_t)512 * 512;
  // phase-2 (DP) workspace, written after phase-1 consumers are done:
  unsigned* TAc = (unsigned*)d_ws;                       // 19.1MB
  float* Vr = (float*)d_ws + (size_t)BB * LDIAG;         // 37.7MB
  unsigned short* Edc = (unsigned short*)(Vr + (size_t)BB * (1536 * LL));  // 9.6MB

  const int nX = 6144 * 512, nW = 512 * 512;
  tobf16<<<(nX / 4 + 255) / 256, 256, 0, stream>>>(hx, hxb, nX);
  tobf16<<<(nX / 4 + 255) / 256, 256, 0, stream>>>(hy, hyb, nX);
  tobf16<<<(nW / 4 + 255) / 256, 256, 0, stream>>>(Wm, Wmb, nW);
  tobf16<<<(nW / 4 + 255) / 256, 256, 0, stream>>>(Wg, Wgb, nW);

  mfma_linear<<<dim3(4, 48, 4), 256, 0, stream>>>(hxb, Wmb, bm, bg, Zb);
  mfma_logits<<<dim3(6, 6, 16), 256, 0, stream>>>(Zb, theta, A);

  row2diag<<<dim3(LL / 64, LL / 64, BB), 256, 0, stream>>>(theta, A, TAc);
  nw_fwd<<<dim3(BB), 192, 0, stream>>>(TAc, Vr);
  nw_bwd<<<dim3(BB), 192, 0, stream>>>(TAc, Vr, Edc);
  diag2row<<<dim3(LL / 64, LL / 64, BB), 256, 0, stream>>>(Edc, aln);
}

// Round 13
// 1658.261 us; speedup vs baseline: 1.4526x; 1.0992x over previous
//
#include <hip/hip_runtime.h>
#include <hip/hip_bf16.h>
#include <math.h>

namespace {

constexpr int BB = 8;
constexpr int LL = 768;
constexpr int DD = 512;
constexpr int L2E = LL * LL;
constexpr int LDIAG = L2E + 8192;
constexpr float NEGF = -1e9f;

typedef __attribute__((ext_vector_type(8))) short bf16x8;
typedef __attribute__((ext_vector_type(8))) unsigned short u16x8;
typedef __attribute__((ext_vector_type(4))) float f32x4;

__device__ __forceinline__ float softplus_f(float x) {
  return x > 0.f ? x + log1pf(expf(-x)) : log1pf(expf(x));
}
__device__ __forceinline__ float logsigmoid_f(float x) {
  return x > 0.f ? -log1pf(expf(-x)) : x - log1pf(expf(x));
}

__device__ __forceinline__ float bf_lo(unsigned u) { return __uint_as_float(u << 16); }
__device__ __forceinline__ float bf_hi(unsigned u) { return __uint_as_float(u & 0xffff0000u); }

__device__ __forceinline__ int lofs(int s) { return (s > LL - 1) ? (s - (LL - 1)) : 0; }

__device__ __forceinline__ int Dmap(int s) {
  if (s <= LL - 1) {
    const int m = s >> 2, i = s & 3;
    const int c = (i == 0) ? 4 : (i == 1) ? 8 : (i == 2) ? 16 : 24;
    return 8 * m * m + (20 + 4 * i) * m + c;
  }
  const int q = (s - LL) >> 2, i = (s - LL) & 3;
  const int base = 298757 + 3092 * q - 8 * q * q;
  const int off = (i == 0) ? 0 : (i == 1) ? (773 - 4 * q)
                : (i == 2) ? (1546 - 8 * q) : (2315 - 12 * q);
  return base + off;
}
__device__ __forceinline__ int dDa(int s) {
  if (s < LL - 1) return s + 4 + ((-s) & 3);
  if (s == LL - 1) return 773;
  return 1539 - s + ((s + 2) & 3);
}
__device__ __forceinline__ int dIa(int s) { return dDa(s) - ((s >= LL - 1) ? 1 : 0); }

// -------- fp32 -> bf16 convert --------
__global__ __launch_bounds__(256) void tobf16(
    const float* __restrict__ src, unsigned short* __restrict__ dst, int n) {
  const int i = (blockIdx.x * 256 + threadIdx.x) * 4;
  if (i < n) {
    const float4 v = *(const float4*)(src + i);
    ushort4 o;
    o.x = __bfloat16_as_ushort(__float2bfloat16(v.x));
    o.y = __bfloat16_as_ushort(__float2bfloat16(v.y));
    o.z = __bfloat16_as_ushort(__float2bfloat16(v.z));
    o.w = __bfloat16_as_ushort(__float2bfloat16(v.w));
    *(ushort4*)(dst + i) = o;
  }
}

// -------- MFMA GEMM 1 --------
__global__ __launch_bounds__(256) void mfma_linear(
    const unsigned short* __restrict__ Xb, const unsigned short* __restrict__ Wb,
    const float* __restrict__ bm, const float* __restrict__ bg,
    unsigned short* __restrict__ Zb) {
  __shared__ unsigned short As[128][32];
  __shared__ unsigned short Bs[128][32];
  const int which = blockIdx.z;
  const unsigned short* X = Xb + (size_t)(which & 1) * (6144 * 512);
  const unsigned short* W = Wb + (size_t)(which >> 1) * (512 * 512);
  const float* bias = (which >= 2) ? bg : bm;
  unsigned short* out = Zb + (size_t)which * (6144 * 512);
  const int row0 = blockIdx.y * 128, col0 = blockIdx.x * 128;
  const int t = threadIdx.x, wv = t >> 6, l = t & 63;
  const int wm = (wv >> 1) * 64, wn = (wv & 1) * 64;

  f32x4 acc[4][4] = {};
  for (int k0 = 0; k0 < 512; k0 += 32) {
#pragma unroll
    for (int c = t; c < 512; c += 256) {
      const int rowi = c >> 2, seg = (c & 3) << 3;
      *(u16x8*)&As[rowi][seg] = *(const u16x8*)&X[(size_t)(row0 + rowi) * 512 + k0 + seg];
      *(u16x8*)&Bs[rowi][seg] = *(const u16x8*)&W[(size_t)(col0 + rowi) * 512 + k0 + seg];
    }
    __syncthreads();
    bf16x8 af[4], bfr[4];
#pragma unroll
    for (int f = 0; f < 4; ++f) {
      af[f]  = *(const bf16x8*)&As[wm + f * 16 + (l & 15)][(l >> 4) << 3];
      bfr[f] = *(const bf16x8*)&Bs[wn + f * 16 + (l & 15)][(l >> 4) << 3];
    }
#pragma unroll
    for (int fm = 0; fm < 4; ++fm)
#pragma unroll
      for (int fn = 0; fn < 4; ++fn)
        acc[fm][fn] = __builtin_amdgcn_mfma_f32_16x16x32_bf16(
            af[fm], bfr[fn], acc[fm][fn], 0, 0, 0);
    __syncthreads();
  }
#pragma unroll
  for (int fm = 0; fm < 4; ++fm) {
    const int rbase = row0 + wm + fm * 16 + ((l >> 4) << 2);
#pragma unroll
    for (int fn = 0; fn < 4; ++fn) {
      const int col = col0 + wn + fn * 16 + (l & 15);
      const float bv = bias[col];
      const f32x4 v = acc[fm][fn];
#pragma unroll
      for (int j = 0; j < 4; ++j)
        out[(size_t)(rbase + j) * 512 + col] =
            __bfloat16_as_ushort(__float2bfloat16(v[j] + bv));
    }
  }
}

// -------- MFMA GEMM 2 --------
__global__ __launch_bounds__(256) void mfma_logits(
    const unsigned short* __restrict__ Zb,
    float* __restrict__ theta, float* __restrict__ Aout) {
  __shared__ unsigned short As[128][32];
  __shared__ unsigned short Bs[128][32];
  const int bz = blockIdx.z;
  const int b = bz >> 1, w = bz & 1;
  const unsigned short* X = Zb + (size_t)(w ? 2 : 0) * (6144 * 512) + (size_t)b * (768 * 512);
  const unsigned short* Y = Zb + (size_t)(w ? 3 : 1) * (6144 * 512) + (size_t)b * (768 * 512);
  float* out = (w ? Aout : theta) + (size_t)b * L2E;
  const int row0 = blockIdx.y * 128, col0 = blockIdx.x * 128;
  const int t = threadIdx.x, wv = t >> 6, l = t & 63;
  const int wm = (wv >> 1) * 64, wn = (wv & 1) * 64;

  f32x4 acc[4][4] = {};
  for (int k0 = 0; k0 < 512; k0 += 32) {
#pragma unroll
    for (int c = t; c < 512; c += 256) {
      const int rowi = c >> 2, seg = (c & 3) << 3;
      *(u16x8*)&As[rowi][seg] = *(const u16x8*)&X[(size_t)(row0 + rowi) * 512 + k0 + seg];
      *(u16x8*)&Bs[rowi][seg] = *(const u16x8*)&Y[(size_t)(col0 + rowi) * 512 + k0 + seg];
    }
    __syncthreads();
    bf16x8 af[4], bfr[4];
#pragma unroll
    for (int f = 0; f < 4; ++f) {
      af[f]  = *(const bf16x8*)&As[wm + f * 16 + (l & 15)][(l >> 4) << 3];
      bfr[f] = *(const bf16x8*)&Bs[wn + f * 16 + (l & 15)][(l >> 4) << 3];
    }
#pragma unroll
    for (int fm = 0; fm < 4; ++fm)
#pragma unroll
      for (int fn = 0; fn < 4; ++fn)
        acc[fm][fn] = __builtin_amdgcn_mfma_f32_16x16x32_bf16(
            af[fm], bfr[fn], acc[fm][fn], 0, 0, 0);
    __syncthreads();
  }
#pragma unroll
  for (int fm = 0; fm < 4; ++fm) {
    const int rbase = row0 + wm + fm * 16 + ((l >> 4) << 2);
#pragma unroll
    for (int fn = 0; fn < 4; ++fn) {
      const int col = col0 + wn + fn * 16 + (l & 15);
      const f32x4 v = acc[fm][fn];
#pragma unroll
      for (int j = 0; j < 4; ++j)
        out[(size_t)(rbase + j) * LL + col] = w ? logsigmoid_f(v[j]) : softplus_f(v[j]);
    }
  }
}

// -------- row-major theta,A -> packed bf16x2 compact-aligned diag --------
__global__ __launch_bounds__(256) void row2diag(
    const float* __restrict__ theta, const float* __restrict__ A,
    unsigned* __restrict__ TAc) {
  __shared__ float tT[64 * 66];
  __shared__ float tA[64 * 66];
  const int b = blockIdx.z;
  const float* inT = theta + (size_t)b * L2E;
  const float* inA = A + (size_t)b * L2E;
  unsigned* out = TAc + (size_t)b * LDIAG;
  const int r0 = blockIdx.y * 64, c0 = blockIdx.x * 64;
  const int t = threadIdx.x, lane = t & 63, grp = t >> 6;
  for (int it = 0; it < 16; ++it) {
    const int rr = it * 4 + grp;
    tT[rr * 66 + lane] = inT[(size_t)(r0 + rr) * LL + c0 + lane];
    tA[rr * 66 + lane] = inA[(size_t)(r0 + rr) * LL + c0 + lane];
  }
  __syncthreads();
  for (int si = grp; si < 127; si += 4) {
    const int s = r0 + c0 + si;
    const int rlo = max(r0, s - c0 - 63);
    const int rhi = min(r0 + 63, s - c0);
    const int base = Dmap(s) - lofs(s);
    const int r = rlo + lane;
    if (r <= rhi) {
      const int ii = (r - r0) * 66 + (s - r - c0);
      const unsigned ut = __bfloat16_as_ushort(__float2bfloat16(tT[ii]));
      const unsigned ua = __bfloat16_as_ushort(__float2bfloat16(tA[ii]));
      out[base + r] = (ua << 16) | ut;
    }
  }
}

// -------- compact-aligned bf16 E -> row-major fp32 (aln) --------
__global__ __launch_bounds__(256) void diag2row(
    const unsigned short* __restrict__ Edc, float* __restrict__ aln) {
  __shared__ float tile[64 * 66];
  const int b = blockIdx.z;
  const int r0 = blockIdx.y * 64;
  const int c0 = blockIdx.x * 64;
  const unsigned short* E = Edc + (size_t)b * LDIAG;
  float* out = aln + (size_t)b * L2E;
  const int t = threadIdx.x;
  const int lane = t & 63;
  const int grp = t >> 6;
  for (int si = grp; si < 127; si += 4) {
    const int s = r0 + c0 + si;
    const int rlo = max(r0, s - c0 - 63);
    const int rhi = min(r0 + 63, s - c0);
    const int base = Dmap(s) - lofs(s);
    const int r = rlo + lane;
    if (r <= rhi) {
      tile[(r - r0) * 66 + (s - r - c0)] =
          __uint_as_float(((unsigned)E[base + r]) << 16);
    }
  }
  __syncthreads();
  for (int it = 0; it < 16; ++it) {
    const int rr = it * 4 + grp;
    out[(size_t)(r0 + rr) * LL + c0 + lane] = tile[rr * 66 + lane];
  }
}

__device__ __forceinline__ void lds_release_store(int* p, int v) {
  asm volatile("s_waitcnt lgkmcnt(0)" ::: "memory");
  __hip_atomic_store(p, v, __ATOMIC_RELAXED, __HIP_MEMORY_SCOPE_WORKGROUP);
}

// -------- NW forward: named-register slots (no arrays), depth 4 --------
__global__ __launch_bounds__(192, 1) void nw_fwd(
    const unsigned* __restrict__ TAc, float* __restrict__ Vr) {
  __shared__ int Pf[4];
  __shared__ float BvF[2][1024];

  const int b = blockIdx.x;
  const unsigned* TA = TAc + (size_t)b * LDIAG;
  float* V = Vr + (size_t)b * (1536 * LL);

  const int t = threadIdx.x;
  const int w = t >> 6, l = t & 63;
  const int rowb = 4 * t;
  const int kb = 256 * w + 2;

  if (t < 4) Pf[t] = 0;
  __syncthreads();

  uint4 q0, q1, q2, q3;
  {
    int s0;
    s0 = kb - 2; q2 = *(const uint4*)(TA + (Dmap(s0) + rowb - lofs(s0)));
    s0 = kb - 1; q3 = *(const uint4*)(TA + (Dmap(s0) + rowb - lofs(s0)));
    s0 = kb;     q0 = *(const uint4*)(TA + (Dmap(s0) + rowb - lofs(s0)));
    s0 = kb + 1; q1 = *(const uint4*)(TA + (Dmap(s0) + rowb - lofs(s0)));
  }
  int sL = kb + 2;
  int iL = Dmap(sL) + rowb - lofs(sL);
  int iS4 = (kb - 2) * LL + rowb;
  float4 p1 = make_float4(NEGF, NEGF, NEGF, NEGF);
  float4 p2 = p1;
  float rvh = NEGF;
  float pv3 = NEGF;

#define FSTEP(U, Q) { \
  const int k = kg + (U); \
  float rv = __shfl_up(pv3, 1); \
  if (l == 0) rv = (w == 0) ? NEGF : BvF[w - 1][min(k - kb + 255, 1023)]; \
  float rdg = rvh; \
  if (l == 0 && w == 0) rdg = (k == 2) ? 0.f : NEGF; \
  const int d = k - rowb - 2; \
  float4 vv; \
  { const float av = bf_hi(Q.x), tv = bf_lo(Q.x); \
    const float lft = av + p1.x, up = av + rv; \
    const float mx = fmaxf(rdg, fmaxf(lft, up)); \
    const float val = tv + mx + __logf(__expf(rdg - mx) + __expf(lft - mx) + __expf(up - mx)); \
    vv.x = ((unsigned)d <= 767u) ? val : NEGF; } \
  { const float av = bf_hi(Q.y), tv = bf_lo(Q.y); \
    const float lft = av + p1.y, up = av + p1.x; \
    const float mx = fmaxf(p2.x, fmaxf(lft, up)); \
    const float val = tv + mx + __logf(__expf(p2.x - mx) + __expf(lft - mx) + __expf(up - mx)); \
    vv.y = ((unsigned)(d - 1) <= 767u) ? val : NEGF; } \
  { const float av = bf_hi(Q.z), tv = bf_lo(Q.z); \
    const float lft = av + p1.z, up = av + p1.y; \
    const float mx = fmaxf(p2.y, fmaxf(lft, up)); \
    const float val = tv + mx + __logf(__expf(p2.y - mx) + __expf(lft - mx) + __expf(up - mx)); \
    vv.z = ((unsigned)(d - 2) <= 767u) ? val : NEGF; } \
  { const float av = bf_hi(Q.w), tv = bf_lo(Q.w); \
    const float lft = av + p1.w, up = av + p1.z; \
    const float mx = fmaxf(p2.z, fmaxf(lft, up)); \
    const float val = tv + mx + __logf(__expf(p2.z - mx) + __expf(lft - mx) + __expf(up - mx)); \
    vv.w = ((unsigned)(d - 3) <= 767u) ? val : NEGF; } \
  Q = *(const uint4*)(TA + iL); \
  iL += dIa(sL); ++sL; \
  *(float4*)(V + iS4) = vv; \
  iS4 += LL; \
  if (l == 63 && w < 2) BvF[w][k - kb] = vv.w; \
  pv3 = vv.w; \
  rvh = rv; \
  p2 = p1; p1 = vv; \
}

  for (int kg = kb; kg < kb + 1024; kg += 8) {
    if (l == 0 && w > 0 && kg < kb + 768) {
      const int need = min(kg + 6, kb + 766);
      while (__hip_atomic_load(&Pf[w - 1], __ATOMIC_ACQUIRE,
                               __HIP_MEMORY_SCOPE_WORKGROUP) < need) {}
    }
    FSTEP(0, q2) FSTEP(1, q3) FSTEP(2, q0) FSTEP(3, q1)
    FSTEP(4, q2) FSTEP(5, q3) FSTEP(6, q0) FSTEP(7, q1)
    if (l == 63 && w < 2) lds_release_store(&Pf[w], kg + 7);
  }
#undef FSTEP
}

// -------- NW backward: named-register slots (no arrays), depth 4 --------
__global__ __launch_bounds__(192, 1) void nw_bwd(
    const unsigned* __restrict__ TAc, const float* __restrict__ Vr,
    unsigned short* __restrict__ Edc) {
  __shared__ int Pb[4];
  __shared__ float Bv2[2][1024];
  __shared__ float Be2[2][1024];

  const int b = blockIdx.x;
  const unsigned* TA = TAc + (size_t)b * LDIAG;
  const float* V = Vr + (size_t)b * (1536 * LL);
  unsigned short* Eo = Edc + (size_t)b * LDIAG;

  const int t = threadIdx.x;
  const int w = t >> 6, l = t & 63;
  const int rowb = 4 * t;
  const int kb = 256 * w + 2;
  const int ke = kb + 1023;

  if (t < 4) Pb[t] = 0x7fffffff;
  __syncthreads();

  float4 V0, V1, V2, V3;
  uint4 K0, K1, K2, K3;
  unsigned F0, F1, F2, F3;
  {
    int sv, sk, ik;
    sv = ke - 2; V1 = *(const float4*)(V + (sv * LL + rowb));
    sk = ke - 1; ik = Dmap(sk) + rowb - lofs(sk);
    K1 = *(const uint4*)(TA + ik); F1 = TA[ik + 4];
    sv = ke - 3; V0 = *(const float4*)(V + (sv * LL + rowb));
    sk = ke - 2; ik = Dmap(sk) + rowb - lofs(sk);
    K0 = *(const uint4*)(TA + ik); F0 = TA[ik + 4];
    sv = ke - 4; V3 = *(const float4*)(V + (sv * LL + rowb));
    sk = ke - 3; ik = Dmap(sk) + rowb - lofs(sk);
    K3 = *(const uint4*)(TA + ik); F3 = TA[ik + 4];
    sv = ke - 5; V2 = *(const float4*)(V + (sv * LL + rowb));
    sk = ke - 4; ik = Dmap(sk) + rowb - lofs(sk);
    K2 = *(const uint4*)(TA + ik); F2 = TA[ik + 4];
  }
  int iV = (ke - 6) * LL + rowb;
  int sK1s = ke - 5;
  int iK1 = Dmap(sK1s) + rowb - lofs(sK1s);
  float4 T0, T1;
  {
    const int j0 = Dmap(ke) + rowb - lofs(ke);
    T0 = make_float4(bf_lo(TA[j0 + 1]), bf_lo(TA[j0 + 2]),
                     bf_lo(TA[j0 + 3]), bf_lo(TA[j0 + 4]));
    T1 = make_float4(0.f, 0.f, 0.f, 0.f);
  }
  int sE = ke - 2;
  int iE = Dmap(sE) + rowb - lofs(sE);
  float4 n1v = {}, n1e = {}, n2v = {}, n2e = {}, hv = {}, he = {};
  float pv0 = 0.f, pe0 = 0.f;

#define BCELL(VCr, DO, ILT, N2Vr, N2Er, TKr, S1a, S1b, N1Vr, N1Er, HVr, HEr, OUT) { \
  const bool ok  = (unsigned)(d - (DO)) <= 767u; \
  const bool jlt = (d - (DO)) < 767; \
  float acc = 0.f; \
  if ((ILT) && jlt) acc += N2Er * __expf(VCr - N2Vr + TKr); \
  if (jlt)          acc += HEr * __expf(bf_hi(S1a) + VCr - HVr + bf_lo(S1a)); \
  if ((ILT))        acc += N1Er * __expf(bf_hi(S1b) + VCr - N1Vr + bf_lo(S1b)); \
  OUT = ok ? acc : 0.f; }

#define BSTEP(U, SV, SK, SF, TRD, TWR) { \
  const int k = kg - (U); \
  { float nv3 = __shfl_down(pv0, 1); \
    float ne3 = __shfl_down(pe0, 1); \
    if (l == 63) { \
      if (w < 2) { const int bi = min(ke - k + 255, 1023); nv3 = Bv2[w][bi]; ne3 = Be2[w][bi]; } \
      else { nv3 = 0.f; ne3 = 0.f; } } \
    n1v.w = nv3; n1e.w = ne3; } \
  const int d = k - rowb - 2; \
  unsigned fifth = __shfl_down(SK.x, 1); \
  if (l == 63) fifth = SF; \
  const float4 vc = SV; \
  float4 ev; \
  BCELL(vc.x, 0, true, n2v.x, n2e.x, TRD.x, SK.x, SK.y, n1v.x, n1e.x, hv.x, he.x, ev.x) \
  BCELL(vc.y, 1, true, n2v.y, n2e.y, TRD.y, SK.y, SK.z, n1v.y, n1e.y, hv.y, he.y, ev.y) \
  BCELL(vc.z, 2, true, n2v.z, n2e.z, TRD.z, SK.z, SK.w, n1v.z, n1e.z, hv.z, he.z, ev.z) \
  BCELL(vc.w, 3, (t != 191), n2v.w, n2e.w, TRD.w, SK.w, fifth, n1v.w, n1e.w, hv.w, he.w, ev.w) \
  if (k == 2 * LL && t == 191) ev.w = 1.f; \
  TWR.x = bf_lo(SK.y); TWR.y = bf_lo(SK.z); TWR.z = bf_lo(SK.w); TWR.w = bf_lo(fifth); \
  SV = *(const float4*)(V + max(iV, 0)); \
  iV -= LL; \
  { const int ic = max(iK1, 0); \
    SK = *(const uint4*)(TA + ic); \
    if (l == 63) SF = TA[ic + 4]; \
    iK1 -= dIa(sK1s - 1); --sK1s; } \
  if ((unsigned)d <= 770u) { \
    ushort4 st; \
    st.x = __bfloat16_as_ushort(__float2bfloat16(ev.x)); \
    st.y = __bfloat16_as_ushort(__float2bfloat16(ev.y)); \
    st.z = __bfloat16_as_ushort(__float2bfloat16(ev.z)); \
    st.w = __bfloat16_as_ushort(__float2bfloat16(ev.w)); \
    *(ushort4*)(Eo + iE) = st; } \
  iE -= dIa(sE - 1); --sE; \
  if (l == 0 && w > 0) { Bv2[w - 1][ke - k] = vc.x; Be2[w - 1][ke - k] = ev.x; } \
  pv0 = vc.x; pe0 = ev.x; \
  n2v = n1v; n2e = n1e; \
  n1v.x = vc.y; n1v.y = vc.z; n1v.z = vc.w; \
  n1e.x = ev.y; n1e.y = ev.z; n1e.z = ev.w; \
  hv = vc; he = ev; \
}

  for (int kg = ke; kg > ke - 1024; kg -= 8) {
    if (l == 63 && w < 2 && kg >= kb + 255) {
      const int need = max(kg - 6, kb + 256);
      while (__hip_atomic_load(&Pb[w + 1], __ATOMIC_ACQUIRE,
                               __HIP_MEMORY_SCOPE_WORKGROUP) > need) {}
    }
    BSTEP(0, V1, K1, F1, T0, T1) BSTEP(1, V0, K0, F0, T1, T0)
    BSTEP(2, V3, K3, F3, T0, T1) BSTEP(3, V2, K2, F2, T1, T0)
    BSTEP(4, V1, K1, F1, T0, T1) BSTEP(5, V0, K0, F0, T1, T0)
    BSTEP(6, V3, K3, F3, T0, T1) BSTEP(7, V2, K2, F2, T1, T0)
    if (l == 0 && w > 0) lds_release_store(&Pb[w], kg - 7);
  }
#undef BSTEP
#undef BCELL
}

}  // namespace

extern "C" void kernel_launch(void* const* d_in, const int* in_sizes, int n_in,
                              void* d_out, int out_size, void* d_ws, size_t ws_size,
                              hipStream_t stream) {
  const float* hx = (const float*)d_in[0];
  const float* hy = (const float*)d_in[1];
  const float* Wm = (const float*)d_in[2];
  const float* bm = (const float*)d_in[3];
  const float* Wg = (const float*)d_in[4];
  const float* bg = (const float*)d_in[5];

  float* aln   = (float*)d_out;
  float* theta = aln + (size_t)BB * L2E;
  float* A     = theta + (size_t)BB * L2E;

  unsigned short* hxb = (unsigned short*)d_ws;
  unsigned short* hyb = hxb + (size_t)6144 * 512;
  unsigned short* Wmb = hyb + (size_t)6144 * 512;
  unsigned short* Wgb = Wmb + (size_t)512 * 512;
  unsigned short* Zb  = Wgb + (size_t)512 * 512;
  unsigned* TAc = (unsigned*)d_ws;
  float* Vr = (float*)d_ws + (size_t)BB * LDIAG;
  unsigned short* Edc = (unsigned short*)(Vr + (size_t)BB * (1536 * LL));

  const int nX = 6144 * 512, nW = 512 * 512;
  tobf16<<<(nX / 4 + 255) / 256, 256, 0, stream>>>(hx, hxb, nX);
  tobf16<<<(nX / 4 + 255) / 256, 256, 0, stream>>>(hy, hyb, nX);
  tobf16<<<(nW / 4 + 255) / 256, 256, 0, stream>>>(Wm, Wmb, nW);
  tobf16<<<(nW / 4 + 255) / 256, 256, 0, stream>>>(Wg, Wgb, nW);

  mfma_linear<<<dim3(4, 48, 4), 256, 0, stream>>>(hxb, Wmb, bm, bg, Zb);
  mfma_logits<<<dim3(6, 6, 16), 256, 0, stream>>>(Zb, theta, A);

  row2diag<<<dim3(LL / 64, LL / 64, BB), 256, 0, stream>>>(theta, A, TAc);
  nw_fwd<<<dim3(BB), 192, 0, stream>>>(TAc, Vr);
  nw_bwd<<<dim3(BB), 192, 0, stream>>>(TAc, Vr, Edc);
  diag2row<<<dim3(LL / 64, LL / 64, BB), 256, 0, stream>>>(Edc, aln);
}